// Round 10
// baseline (563.749 us; speedup 1.0000x reference)
//
#include <hip/hip_runtime.h>
#include <math.h>

#define B_SZ 2
#define N_SEQ 2048
#define DM 1024
#define H_HEADS 16
#define DH 64
#define KC 32
#define TOPK 100
#define TQ 16
#define KT 128
#define NTMAX 16
#define FCAP 192
#define CSTRIDE 132

typedef _Float16 half2_t __attribute__((ext_vector_type(2)));
typedef _Float16 half4_t __attribute__((ext_vector_type(4)));
typedef _Float16 half8_t __attribute__((ext_vector_type(8)));
typedef float floatx4 __attribute__((ext_vector_type(4)));
typedef unsigned short ushort4_t __attribute__((ext_vector_type(4)));

// ---------- helpers ----------
__device__ __forceinline__ unsigned short h2us(_Float16 h) {
  unsigned short u; __builtin_memcpy(&u, &h, 2); return u;
}
__device__ __forceinline__ _Float16 us2h(unsigned short u) {
  _Float16 h; __builtin_memcpy(&h, &u, 2); return h;
}
__device__ __forceinline__ unsigned okey16(unsigned short us) {
  return (us & 0x8000u) ? (unsigned)(unsigned short)~us
                        : (unsigned)(us | 0x8000u);
}

// async global->LDS, 16 B per lane; lds_base must be wave-uniform
__device__ __forceinline__ void stage16(const _Float16* g, _Float16* lds_base,
                                        int lane) {
#if __has_builtin(__builtin_amdgcn_global_load_lds)
  __builtin_amdgcn_global_load_lds(
      (const __attribute__((address_space(1))) void*)g,
      (__attribute__((address_space(3))) void*)lds_base, 16, 0, 0);
#else
  *(half8_t*)(lds_base + lane * 8) = *(const half8_t*)g;
#endif
}

// ---------- merged setup: cast_x (4096 blk) + rope (256 blk) + const (1 blk)
__global__ __launch_bounds__(256) void setup_kernel(
    const float* __restrict__ x, _Float16* __restrict__ xh,
    float* __restrict__ cosT, float* __restrict__ sinT,
    float* __restrict__ wre, float* __restrict__ wim) {
  const int bi = blockIdx.x;
  if (bi < 4096) {
    // cast x fp32 -> fp16
    int idx = bi * 256 + threadIdx.x;
    float4 v = ((const float4*)x)[idx];
    half4_t h;
    h[0] = (_Float16)v.x; h[1] = (_Float16)v.y;
    h[2] = (_Float16)v.z; h[3] = (_Float16)v.w;
    ((half4_t*)xh)[idx] = h;
  } else if (bi < 4096 + 256) {
    // RoPE tables (f32 math; err far under fp16 quantization downstream)
    int idx = (bi - 4096) * 256 + threadIdx.x;  // 65536 = 2048*32
    int kk = idx & 31, n = idx >> 5;
    float f = -(float)kk * (13.2877123795494f / 32.0f);
    float inv_freq = exp2f(f);
    float ph = (float)n * inv_freq;
    cosT[idx] = cosf(ph);
    sinT[idx] = sinf(ph);
  } else {
    // Riemann-zero weights (32 active threads)
    __shared__ double g0s;
    const int k = threadIdx.x;
    const double PI = 3.14159265358979323846;
    const double E_ = 2.71828182845904523536;
    double t = 0.0;
    if (k < 32) {
      double n = (double)(k + 1);
      t = 10.0 + 6.0 * n;
      for (int it = 0; it < 16; ++it) {
        double f  = t / (2.0 * PI) * log(t / (2.0 * PI * E_)) - (n - 0.875);
        double fp = log(t / (2.0 * PI)) / (2.0 * PI);
        t = t - f / fp;
      }
      if (k == 0) g0s = t;
    }
    __syncthreads();
    if (k < 32) {
      double g = t / g0s;
      double denom = 0.25 + g * g;
      wre[k] = (float)(0.5 / denom);
      wim[k] = (float)(-g / denom);
    }
  }
}

// ---------- transpose-cast W (fp32 [k][n]) -> Wt (fp16 [n][k]) ----------
__global__ __launch_bounds__(256) void transpose_cast(
    const float* __restrict__ W0, const float* __restrict__ W1,
    const float* __restrict__ W2, const float* __restrict__ W3,
    _Float16* __restrict__ T0, _Float16* __restrict__ T1,
    _Float16* __restrict__ T2, _Float16* __restrict__ T3) {
  __shared__ float t[64][65];
  const float* W; _Float16* T;
  switch (blockIdx.z) {
    case 0: W = W0; T = T0; break;
    case 1: W = W1; T = T1; break;
    case 2: W = W2; T = T2; break;
    default: W = W3; T = T3; break;
  }
  const int bx = blockIdx.x;  // k block
  const int by = blockIdx.y;  // n block
  const int tid = threadIdx.x;
  const int c = tid & 15, rr = tid >> 4;
#pragma unroll
  for (int i = 0; i < 4; ++i) {
    int k = rr + i * 16;
    float4 v = *(const float4*)(W + (size_t)(bx * 64 + k) * DM + by * 64 + c * 4);
    t[k][c * 4 + 0] = v.x; t[k][c * 4 + 1] = v.y;
    t[k][c * 4 + 2] = v.z; t[k][c * 4 + 3] = v.w;
  }
  __syncthreads();
#pragma unroll
  for (int i = 0; i < 4; ++i) {
    int n = rr + i * 16;
    half4_t h;
    h[0] = (_Float16)t[c * 4 + 0][n];
    h[1] = (_Float16)t[c * 4 + 1][n];
    h[2] = (_Float16)t[c * 4 + 2][n];
    h[3] = (_Float16)t[c * 4 + 3][n];
    *(half4_t*)(T + (size_t)(by * 64 + n) * DM + bx * 64 + c * 4) = h;
  }
}

// ---------- shared GEMM main loop (BK=64, rule-21 XOR swizzle, R4-verified) -
__device__ __forceinline__ void gemm_loop(const _Float16* __restrict__ A,
                                          const _Float16* __restrict__ Bt,
                                          _Float16* As, _Float16* Bs,
                                          int bm, int bn,
                                          floatx4 (&acc)[4][4]) {
  const int tid = threadIdx.x;
  const int wave = tid >> 6, lane = tid & 63;
  const int wm = wave >> 1, wn = wave & 1;
  const int grow = lane >> 3;           // row within 8-row staging segment
  const int gch  = (lane & 7) ^ grow;   // pre-swizzled source chunk (8 halves)
  const int l16 = lane & 15, lq = lane >> 4;
  const int sw  = l16 & 7;              // row&7 for swizzled reads

  for (int k0 = 0; k0 < DM; k0 += 64) {
    __syncthreads();
#pragma unroll
    for (int s = 0; s < 4; ++s) {
      const int seg = wave * 4 + s;  // 8-row segment of the 128-row tile
      stage16(A + (size_t)(bm + seg * 8 + grow) * DM + k0 + gch * 8,
              As + seg * 512, lane);
      stage16(Bt + (size_t)(bn + seg * 8 + grow) * DM + k0 + gch * 8,
              Bs + seg * 512, lane);
    }
    __syncthreads();
    half8_t af[2][4], bf[2][4];
#pragma unroll
    for (int kk2 = 0; kk2 < 2; ++kk2) {
#pragma unroll
      for (int mi = 0; mi < 4; ++mi)
        af[kk2][mi] = *(const half8_t*)(As + (wm * 64 + mi * 16 + l16) * 64 +
                                        ((kk2 * 4 + lq) ^ sw) * 8);
#pragma unroll
      for (int ni = 0; ni < 4; ++ni)
        bf[kk2][ni] = *(const half8_t*)(Bs + (wn * 64 + ni * 16 + l16) * 64 +
                                        ((kk2 * 4 + lq) ^ sw) * 8);
    }
#pragma unroll
    for (int kk2 = 0; kk2 < 2; ++kk2)
#pragma unroll
      for (int mi = 0; mi < 4; ++mi)
#pragma unroll
        for (int ni = 0; ni < 4; ++ni)
          acc[mi][ni] = __builtin_amdgcn_mfma_f32_16x16x32_f16(
              af[kk2][mi], bf[kk2][ni], acc[mi][ni], 0, 0, 0);
  }
}

// XCD-aware bijective swizzle for a 256-block z-plane (m204; 256 = 8*32):
// dispatch d -> orig block (d%8)*32 + d/8, so each XCD gets 32 contiguous
// orig blocks = 4 bm A-panels (1 MB) + 8 bn B-panels (2 MB) -> L2-resident.
__device__ __forceinline__ void xcd_decode(int flat, int& bm, int& bn) {
  const int o = (flat & 7) * 32 + (flat >> 3);
  bm = (o >> 3) * 128;
  bn = (o & 7) * 128;
}

// ---------- fused QKV GEMM: LDS-coalesced epilogue (RoPE + w + layout) ------
__global__ __launch_bounds__(256) void gemm_qkv_fused(
    const _Float16* __restrict__ xh, const _Float16* __restrict__ Wt0,
    const _Float16* __restrict__ Wt1, const _Float16* __restrict__ Wt2,
    const float* __restrict__ wre, const float* __restrict__ wim,
    const float* __restrict__ cosT, const float* __restrict__ sinT,
    float* __restrict__ qhO, _Float16* __restrict__ kthO,
    _Float16* __restrict__ vthO) {
  __shared__ __align__(16) _Float16 smem[2 * 128 * 64];  // 32 KB
  _Float16* As = smem;
  _Float16* Bs = smem + 128 * 64;
  const int z = blockIdx.z;
  const _Float16* Bt = (z == 0) ? Wt0 : (z == 1) ? Wt1 : Wt2;
  int bm, bn;
  xcd_decode(blockIdx.x, bm, bn);
  floatx4 acc[4][4] = {};
  gemm_loop(xh, Bt, As, Bs, bm, bn, acc);
  __syncthreads();  // all ds_reads of the last tile done before smem reuse

  float* cbuf = (float*)smem;  // [32][CSTRIDE] = 16896 B, fits in 32 KB
  const int tid = threadIdx.x;
  const int wave = tid >> 6, lane = tid & 63;
  const int wm = wave >> 1, wn = wave & 1;
  const int l16 = lane & 15, lq = lane >> 4;

  // read-phase mapping: 2 heads x 32 rows x 4 kk-octets
  const int h2 = tid >> 7, t7 = tid & 127;
  const int rl = t7 >> 2, q4 = t7 & 3;
  const int hh = (bn >> 6) + h2;
  const int row_nom = bm + (rl >> 4) * 64 + (rl & 15);  // + mi*16 in loop
  const int kk0 = q4 * 8;

#pragma unroll
  for (int mi = 0; mi < 4; ++mi) {
    // scatter: 32 rows x 128 cols of C, f32
#pragma unroll
    for (int ni = 0; ni < 4; ++ni)
#pragma unroll
      for (int r = 0; r < 4; ++r)
        cbuf[(wm * 16 + lq * 4 + r) * CSTRIDE + wn * 64 + ni * 16 + l16] =
            acc[mi][ni][r];
    __syncthreads();

    const int row = row_nom + mi * 16;
    const int b = row >> 11, n = row & (N_SEQ - 1);
    const float* crow = cbuf + rl * CSTRIDE + h2 * 64;
    const size_t base = ((size_t)((b * H_HEADS + hh) * N_SEQ + n)) * DH;

    if (z == 2) {
      const int d0 = q4 * 16;
      half8_t o0, o1;
#pragma unroll
      for (int j = 0; j < 8; ++j) {
        o0[j] = (_Float16)crow[d0 + j];
        o1[j] = (_Float16)crow[d0 + 8 + j];
      }
      *(half8_t*)(vthO + base + d0) = o0;
      *(half8_t*)(vthO + base + d0 + 8) = o1;
    } else if (z == 1) {
      const float sj = 0.125f * sqrtf(1.0f + (float)n);
      half8_t ore, oim;
#pragma unroll
      for (int j = 0; j < 8; ++j) {
        const int kk = kk0 + j;
        const float re = crow[2 * kk], im = crow[2 * kk + 1];
        const float cp = cosT[n * 32 + kk], sp = sinT[n * 32 + kk];
        ore[j] = (_Float16)((cp * re + sp * im) * sj);
        oim[j] = (_Float16)((cp * im - sp * re) * sj);
      }
      *(half8_t*)(kthO + base + kk0) = ore;
      *(half8_t*)(kthO + base + 32 + kk0) = oim;
    } else {
      float ore[8], oim[8];
#pragma unroll
      for (int j = 0; j < 8; ++j) {
        const int kk = kk0 + j;
        const float re = crow[2 * kk], im = crow[2 * kk + 1];
        const float cp = cosT[n * 32 + kk], sp = sinT[n * 32 + kk];
        const float t_re = cp * re + sp * im;
        const float t_im = cp * im - sp * re;
        const float wr = wre[kk], wi = wim[kk];
        ore[j] = wr * t_re - wi * t_im;
        oim[j] = wr * t_im + wi * t_re;
      }
      float4 v0 = {ore[0], ore[1], ore[2], ore[3]};
      float4 v1 = {ore[4], ore[5], ore[6], ore[7]};
      float4 v2 = {oim[0], oim[1], oim[2], oim[3]};
      float4 v3 = {oim[4], oim[5], oim[6], oim[7]};
      *(float4*)(qhO + base + kk0) = v0;
      *(float4*)(qhO + base + kk0 + 4) = v1;
      *(float4*)(qhO + base + 32 + kk0) = v2;
      *(float4*)(qhO + base + 32 + kk0 + 4) = v3;
    }
    if (mi < 3) __syncthreads();
  }
}

// ---------- output GEMM (plain epilogue) ----------
__global__ __launch_bounds__(256) void gemm_out_mfma(
    const _Float16* __restrict__ A, const _Float16* __restrict__ Bt,
    float* __restrict__ C) {
  __shared__ _Float16 As[128 * 64];
  __shared__ _Float16 Bs[128 * 64];
  int bm, bn;
  xcd_decode(blockIdx.x, bm, bn);
  floatx4 acc[4][4] = {};
  gemm_loop(A, Bt, As, Bs, bm, bn, acc);
  const int tid = threadIdx.x;
  const int wave = tid >> 6, lane = tid & 63;
  const int wm = wave >> 1, wn = wave & 1;
  const int l16 = lane & 15, lq = lane >> 4;
#pragma unroll
  for (int mi = 0; mi < 4; ++mi)
#pragma unroll
    for (int ni = 0; ni < 4; ++ni) {
      const int col = bn + wn * 64 + ni * 16 + l16;
#pragma unroll
      for (int r = 0; r < 4; ++r) {
        const int row = bm + wm * 64 + mi * 16 + lq * 4 + r;
        C[(size_t)row * DM + col] = acc[mi][ni][r];
      }
    }
}

// ---------- attention: R9 structure (no K staging) + dual-chain PV ----------
__global__ __launch_bounds__(512, 4) void attn_kernel(
    const float* __restrict__ qh, const _Float16* __restrict__ kth,
    const _Float16* __restrict__ vth, _Float16* __restrict__ oh) {
  __shared__ unsigned hist[TQ][128];                  // 8192 B packed 16-bit
  __shared__ unsigned final_[TQ][FCAP];               // 12288 B (p<<16)|j
  __shared__ float mredw[8][TQ];                      // 512 B
  __shared__ float rowm[TQ], rowsum[TQ];
  __shared__ unsigned cnt2[TQ], tkA[TQ];
  __shared__ int sh_b[TQ], sh_k[TQ];

  const int tile = gridDim.x - 1 - blockIdx.x;  // heavy blocks first
  const int bh   = blockIdx.y;                  // 0..31
  const int i0   = tile * TQ;
  const int tid  = threadIdx.x;
  const int wv = tid >> 6, lane = tid & 63;
  const int l16 = lane & 15, lq = lane >> 4;
  const int jbase = wv * 16 + l16;              // col within a 128-wide tile

  const _Float16* kbase = kth + (size_t)bh * N_SEQ * DH;
  const _Float16* vbase = vth + (size_t)bh * N_SEQ * DH;
  // per-lane K fragment base: row jbase, halves [lq*8..lq*8+8) and +32
  const _Float16* kfrag = kbase + (size_t)jbase * DH + lq * 8;

  // ---- init ----
#pragma unroll
  for (int u = 0; u < 4; ++u) ((unsigned*)hist)[u * 512 + tid] = 0;
  if (tid < TQ) { cnt2[tid] = 0; rowsum[tid] = 0.f; }

  // ---- A-fragment: row m=l16 -> q row i0+l16, k=lq*8+j (K=64 via 2 mfma) ----
  half8_t af0, af1;
  {
    const float* qrow = qh + ((size_t)(bh * N_SEQ + i0 + l16)) * DH;
    const float rs = rsqrtf(1.0f + (float)(i0 + l16));
    float4 a0 = *(const float4*)(qrow + lq * 8);
    float4 a1 = *(const float4*)(qrow + lq * 8 + 4);
    float4 b0 = *(const float4*)(qrow + 32 + lq * 8);
    float4 b1 = *(const float4*)(qrow + 32 + lq * 8 + 4);
    af0[0] = (_Float16)(a0.x * rs); af0[1] = (_Float16)(a0.y * rs);
    af0[2] = (_Float16)(a0.z * rs); af0[3] = (_Float16)(a0.w * rs);
    af0[4] = (_Float16)(a1.x * rs); af0[5] = (_Float16)(a1.y * rs);
    af0[6] = (_Float16)(a1.z * rs); af0[7] = (_Float16)(a1.w * rs);
    af1[0] = (_Float16)(b0.x * rs); af1[1] = (_Float16)(b0.y * rs);
    af1[2] = (_Float16)(b0.z * rs); af1[3] = (_Float16)(b0.w * rs);
    af1[4] = (_Float16)(b1.x * rs); af1[5] = (_Float16)(b1.y * rs);
    af1[6] = (_Float16)(b1.z * rs); af1[7] = (_Float16)(b1.w * rs);
  }

  const int ntile = (i0 + TQ + KT - 1) / KT;  // uniform across block, <= 16

  ushort4_t scr[NTMAX];  // 64 fp16 scores, static indexing only
  float mx[4] = {-INFINITY, -INFINITY, -INFINITY, -INFINITY};

  __syncthreads();  // hist zero-init visible to all before pass A atomics

  // ---- pass A: barrier-free MFMA sweep. scores -> regs, hist, row max ----
#pragma unroll
  for (int t = 0; t < NTMAX; ++t) {
    if (t < ntile) {  // block-uniform
      const _Float16* kp = kfrag + (size_t)t * KT * DH;
      half8_t bf0 = *(const half8_t*)kp;
      half8_t bf1 = *(const half8_t*)(kp + 32);
      floatx4 acc = {};
      acc = __builtin_amdgcn_mfma_f32_16x16x32_f16(af0, bf0, acc, 0, 0, 0);
      acc = __builtin_amdgcn_mfma_f32_16x16x32_f16(af1, bf1, acc, 0, 0, 0);
      const int jc = t * KT + jbase;
      ushort4_t s4;
#pragma unroll
      for (int r = 0; r < 4; ++r) {
        float sc = acc[r];
        s4[r] = h2us((_Float16)sc);
        if (jc <= i0 + lq * 4 + r) {
          mx[r] = fmaxf(mx[r], sc);
          unsigned hb = okey16(s4[r]) >> 8;
          atomicAdd(&hist[lq * 4 + r][hb >> 1], 1u << ((hb & 1) * 16));
        }
      }
      scr[t] = s4;
    }
  }

  // ---- row max: reduce over 16-lane group, then over 8 waves ----
#pragma unroll
  for (int g = 1; g <= 8; g <<= 1)
#pragma unroll
    for (int r = 0; r < 4; ++r) mx[r] = fmaxf(mx[r], __shfl_xor(mx[r], g));
  if (l16 == 0)
#pragma unroll
    for (int r = 0; r < 4; ++r) mredw[wv][lq * 4 + r] = mx[r];
  __syncthreads();
  if (tid < TQ) {
    float m = mredw[0][tid];
#pragma unroll
    for (int w = 1; w < 8; ++w) m = fmaxf(m, mredw[w][tid]);
    rowm[tid] = m;
  }

  // ---- parallel hi-byte select: 32 threads/row, 8 bins/thread, suffix scan -
  const int srow = tid >> 5, ts = tid & 31;
  {
    const int L = i0 + srow + 1;
    if (L > TOPK) {
      const unsigned* hrow = hist[srow];
      const int base_u = 124 - 4 * ts;  // bins 255-8ts .. 248-8ts descending
      unsigned h0 = hrow[base_u + 0], h1 = hrow[base_u + 1];
      unsigned h2 = hrow[base_u + 2], h3 = hrow[base_u + 3];
      int c[8] = {(int)(h3 >> 16), (int)(h3 & 0xffffu),
                  (int)(h2 >> 16), (int)(h2 & 0xffffu),
                  (int)(h1 >> 16), (int)(h1 & 0xffffu),
                  (int)(h0 >> 16), (int)(h0 & 0xffffu)};
      int ssum = 0;
#pragma unroll
      for (int k2 = 0; k2 < 8; ++k2) ssum += c[k2];
      int inc = ssum;
#pragma unroll
      for (int d = 1; d < 32; d <<= 1) {
        int o = __shfl_up(inc, d, 32);
        if (ts >= d) inc += o;
      }
      const int excl = inc - ssum;
      if (excl < TOPK && TOPK <= inc) {  // crossing lives in my 8 bins
        int cum = excl, k2 = 0;
#pragma unroll
        for (; k2 < 8; ++k2) {
          if (cum + c[k2] >= TOPK) break;
          cum += c[k2];
        }
        sh_b[srow] = 255 - 8 * ts - k2;
        sh_k[srow] = TOPK - cum;
      }
    } else if (ts == 0) {
      sh_b[srow] = 256;  // no hi-byte matches -> pass B no-op for this row
      sh_k[srow] = 0;
      tkA[srow] = 0;     // all valid entries survive
    }
  }
  __syncthreads();
#pragma unroll
  for (int u = 0; u < 4; ++u) ((unsigned*)hist)[u * 512 + tid] = 0;
  int bh4[4];
#pragma unroll
  for (int r = 0; r < 4; ++r) bh4[r] = sh_b[lq * 4 + r];
  __syncthreads();

  // ---- pass B: register scan -> lo-byte hist of the threshold bucket ----
#pragma unroll
  for (int t = 0; t < NTMAX; ++t) {
    if (t < ntile) {
      const int jc = t * KT + jbase;
      ushort4_t s4 = scr[t];
#pragma unroll
      for (int r = 0; r < 4; ++r) {
        if (jc <= i0 + lq * 4 + r) {
          unsigned key = okey16(s4[r]);
          if ((int)(key >> 8) == bh4[r]) {
            unsigned lb = key & 255u;
            atomicAdd(&hist[lq * 4 + r][lb >> 1], 1u << ((lb & 1) * 16));
          }
        }
      }
    }
  }
  __syncthreads();

  // ---- parallel lo-byte select -> exact fp16 threshold key ----
  {
    const int L = i0 + srow + 1;
    if (L > TOPK) {
      const int krem = sh_k[srow];
      const unsigned* hrow = hist[srow];
      const int base_u = 124 - 4 * ts;
      unsigned h0 = hrow[base_u + 0], h1 = hrow[base_u + 1];
      unsigned h2 = hrow[base_u + 2], h3 = hrow[base_u + 3];
      int c[8] = {(int)(h3 >> 16), (int)(h3 & 0xffffu),
                  (int)(h2 >> 16), (int)(h2 & 0xffffu),
                  (int)(h1 >> 16), (int)(h1 & 0xffffu),
                  (int)(h0 >> 16), (int)(h0 & 0xffffu)};
      int ssum = 0;
#pragma unroll
      for (int k2 = 0; k2 < 8; ++k2) ssum += c[k2];
      int inc = ssum;
#pragma unroll
      for (int d = 1; d < 32; d <<= 1) {
        int o = __shfl_up(inc, d, 32);
        if (ts >= d) inc += o;
      }
      const int excl = inc - ssum;
      if (excl < krem && krem <= inc) {
        int cum = excl, k2 = 0;
#pragma unroll
        for (; k2 < 8; ++k2) {
          if (cum + c[k2] >= krem) break;
          cum += c[k2];
        }
        tkA[srow] = ((unsigned)sh_b[srow] << 8) | (unsigned)(255 - 8 * ts - k2);
      }
    }
  }
  __syncthreads();

  // ---- pass C: register scan -> survivors + exp, direct append ----
  unsigned tk4[4]; float m4[4];
#pragma unroll
  for (int r = 0; r < 4; ++r) {
    tk4[r] = tkA[lq * 4 + r];
    m4[r]  = rowm[lq * 4 + r];
  }
  float lsum[4] = {0.f, 0.f, 0.f, 0.f};
#pragma unroll
  for (int t = 0; t < NTMAX; ++t) {
    if (t < ntile) {
      const int jc = t * KT + jbase;
      ushort4_t s4 = scr[t];
#pragma unroll
      for (int r = 0; r < 4; ++r) {
        if (jc <= i0 + lq * 4 + r) {
          unsigned short us = s4[r];
          if (okey16(us) >= tk4[r]) {
            float p = __expf((float)us2h(us) - m4[r]);
            lsum[r] += p;
            unsigned pos = atomicAdd(&cnt2[lq * 4 + r], 1u);
            if (pos < FCAP)
              final_[lq * 4 + r][pos] =
                  ((unsigned)h2us((_Float16)p) << 16) | (unsigned)jc;
          }
        }
      }
    }
  }
#pragma unroll
  for (int g = 1; g <= 8; g <<= 1)
#pragma unroll
    for (int r = 0; r < 4; ++r) lsum[r] += __shfl_xor(lsum[r], g);
  if (l16 == 0)
#pragma unroll
    for (int r = 0; r < 4; ++r) atomicAdd(&rowsum[lq * 4 + r], lsum[r]);
  __syncthreads();

  // ---- sparse p @ V: two independent row-chains per wave (2x MLP), x8 unroll
  {
    const int r0 = wv, r1 = wv + 8;
    const int n0 = (int)min(cnt2[r0], (unsigned)FCAP);
    const int n1 = (int)min(cnt2[r1], (unsigned)FCAP);
    const float inv0 = 1.0f / rowsum[r0];
    const float inv1 = 1.0f / rowsum[r1];
    float a0 = 0.f, a1 = 0.f;
    const int nmx = n0 > n1 ? n0 : n1;
#pragma unroll 8
    for (int s = 0; s < nmx; ++s) {
      if (s < n0) {
        unsigned e = final_[r0][s];
        a0 += (float)us2h((unsigned short)(e >> 16)) *
              (float)vbase[(size_t)(e & 0xffffu) * DH + lane];
      }
      if (s < n1) {
        unsigned e = final_[r1][s];
        a1 += (float)us2h((unsigned short)(e >> 16)) *
              (float)vbase[(size_t)(e & 0xffffu) * DH + lane];
      }
    }
    const int b = bh >> 4, h = bh & 15;
    oh[((size_t)(b * N_SEQ + i0 + r0)) * DM + h * DH + lane] =
        (_Float16)(a0 * inv0);
    oh[((size_t)(b * N_SEQ + i0 + r1)) * DM + h * DH + lane] =
        (_Float16)(a1 * inv1);
  }
}

// ---------- launch ----------
extern "C" void kernel_launch(void* const* d_in, const int* in_sizes, int n_in,
                              void* d_out, int out_size, void* d_ws, size_t ws_size,
                              hipStream_t stream) {
  const float* x  = (const float*)d_in[0];
  const float* Wq = (const float*)d_in[1];
  const float* Wk = (const float*)d_in[2];
  const float* Wv = (const float*)d_in[3];
  const float* Wo = (const float*)d_in[4];
  float* out = (float*)d_out;
  char* ws = (char*)d_ws;

  const size_t MAT = (size_t)B_SZ * N_SEQ * DM;  // 4,194,304 elements
  const size_t WSZ = (size_t)DM * DM;            // 1,048,576

  float*    qh   = (float*)ws;                       ws += MAT * 4;   // 16 MB
  _Float16* xh   = (_Float16*)ws;                    ws += MAT * 2;   // 8 MB
  _Float16* kth  = (_Float16*)ws;                    ws += MAT * 2;
  _Float16* vth  = (_Float16*)ws;                    ws += MAT * 2;
  _Float16* Wt0  = (_Float16*)ws;                    ws += WSZ * 2;
  _Float16* Wt1  = (_Float16*)ws;                    ws += WSZ * 2;
  _Float16* Wt2  = (_Float16*)ws;                    ws += WSZ * 2;
  _Float16* Wt3  = (_Float16*)ws;                    ws += WSZ * 2;
  float*    wre  = (float*)ws;                       ws += KC * 4;
  float*    wim  = (float*)ws;                       ws += KC * 4;
  float*    cosT = (float*)ws;                       ws += (size_t)N_SEQ * KC * 4;
  float*    sinT = (float*)ws;                       ws += (size_t)N_SEQ * KC * 4;
  _Float16* oh   = xh;  // xh dead after QKV GEMM; reuse for attn output

  setup_kernel<<<4096 + 256 + 1, 256, 0, stream>>>(x, xh, cosT, sinT, wre, wim);
  transpose_cast<<<dim3(16, 16, 4), 256, 0, stream>>>(Wq, Wk, Wv, Wo,
                                                      Wt0, Wt1, Wt2, Wt3);
  gemm_qkv_fused<<<dim3(256, 1, 3), 256, 0, stream>>>(
      xh, Wt0, Wt1, Wt2, wre, wim, cosT, sinT, qh, kth, vth);
  attn_kernel<<<dim3(N_SEQ / TQ, B_SZ * H_HEADS), 512, 0, stream>>>(
      qh, kth, vth, oh);
  gemm_out_mfma<<<dim3(256), 256, 0, stream>>>(oh, Wt3, out);
}

// Round 11
// 388.555 us; speedup vs baseline: 1.4509x; 1.4509x over previous
//
#include <hip/hip_runtime.h>
#include <math.h>

#define B_SZ 2
#define N_SEQ 2048
#define DM 1024
#define H_HEADS 16
#define DH 64
#define KC 32
#define TOPK 100
#define TQ 16
#define KT 128
#define NTMAX 16
#define FCAP 192
#define CSTRIDE 132

typedef _Float16 half2_t __attribute__((ext_vector_type(2)));
typedef _Float16 half4_t __attribute__((ext_vector_type(4)));
typedef _Float16 half8_t __attribute__((ext_vector_type(8)));
typedef float floatx4 __attribute__((ext_vector_type(4)));
typedef unsigned short ushort4_t __attribute__((ext_vector_type(4)));

// ---------- helpers ----------
__device__ __forceinline__ unsigned short h2us(_Float16 h) {
  unsigned short u; __builtin_memcpy(&u, &h, 2); return u;
}
__device__ __forceinline__ _Float16 us2h(unsigned short u) {
  _Float16 h; __builtin_memcpy(&h, &u, 2); return h;
}
__device__ __forceinline__ unsigned okey16(unsigned short us) {
  return (us & 0x8000u) ? (unsigned)(unsigned short)~us
                        : (unsigned)(us | 0x8000u);
}

// async global->LDS, 16 B per lane; lds_base must be wave-uniform
__device__ __forceinline__ void stage16(const _Float16* g, _Float16* lds_base,
                                        int lane) {
#if __has_builtin(__builtin_amdgcn_global_load_lds)
  __builtin_amdgcn_global_load_lds(
      (const __attribute__((address_space(1))) void*)g,
      (__attribute__((address_space(3))) void*)lds_base, 16, 0, 0);
#else
  *(half8_t*)(lds_base + lane * 8) = *(const half8_t*)g;
#endif
}

// ---------- merged setup: cast_x (4096 blk) + rope (256 blk) + const (1 blk)
__global__ __launch_bounds__(256) void setup_kernel(
    const float* __restrict__ x, _Float16* __restrict__ xh,
    float* __restrict__ cosT, float* __restrict__ sinT,
    float* __restrict__ wre, float* __restrict__ wim) {
  const int bi = blockIdx.x;
  if (bi < 4096) {
    // cast x fp32 -> fp16
    int idx = bi * 256 + threadIdx.x;
    float4 v = ((const float4*)x)[idx];
    half4_t h;
    h[0] = (_Float16)v.x; h[1] = (_Float16)v.y;
    h[2] = (_Float16)v.z; h[3] = (_Float16)v.w;
    ((half4_t*)xh)[idx] = h;
  } else if (bi < 4096 + 256) {
    // RoPE tables (f32 math; err far under fp16 quantization downstream)
    int idx = (bi - 4096) * 256 + threadIdx.x;  // 65536 = 2048*32
    int kk = idx & 31, n = idx >> 5;
    float f = -(float)kk * (13.2877123795494f / 32.0f);
    float inv_freq = exp2f(f);
    float ph = (float)n * inv_freq;
    cosT[idx] = cosf(ph);
    sinT[idx] = sinf(ph);
  } else {
    // Riemann-zero weights (32 active threads)
    __shared__ double g0s;
    const int k = threadIdx.x;
    const double PI = 3.14159265358979323846;
    const double E_ = 2.71828182845904523536;
    double t = 0.0;
    if (k < 32) {
      double n = (double)(k + 1);
      t = 10.0 + 6.0 * n;
      for (int it = 0; it < 16; ++it) {
        double f  = t / (2.0 * PI) * log(t / (2.0 * PI * E_)) - (n - 0.875);
        double fp = log(t / (2.0 * PI)) / (2.0 * PI);
        t = t - f / fp;
      }
      if (k == 0) g0s = t;
    }
    __syncthreads();
    if (k < 32) {
      double g = t / g0s;
      double denom = 0.25 + g * g;
      wre[k] = (float)(0.5 / denom);
      wim[k] = (float)(-g / denom);
    }
  }
}

// ---------- transpose-cast W (fp32 [k][n]) -> Wt (fp16 [n][k]) ----------
__global__ __launch_bounds__(256) void transpose_cast(
    const float* __restrict__ W0, const float* __restrict__ W1,
    const float* __restrict__ W2, const float* __restrict__ W3,
    _Float16* __restrict__ T0, _Float16* __restrict__ T1,
    _Float16* __restrict__ T2, _Float16* __restrict__ T3) {
  __shared__ float t[64][65];
  const float* W; _Float16* T;
  switch (blockIdx.z) {
    case 0: W = W0; T = T0; break;
    case 1: W = W1; T = T1; break;
    case 2: W = W2; T = T2; break;
    default: W = W3; T = T3; break;
  }
  const int bx = blockIdx.x;  // k block
  const int by = blockIdx.y;  // n block
  const int tid = threadIdx.x;
  const int c = tid & 15, rr = tid >> 4;
#pragma unroll
  for (int i = 0; i < 4; ++i) {
    int k = rr + i * 16;
    float4 v = *(const float4*)(W + (size_t)(bx * 64 + k) * DM + by * 64 + c * 4);
    t[k][c * 4 + 0] = v.x; t[k][c * 4 + 1] = v.y;
    t[k][c * 4 + 2] = v.z; t[k][c * 4 + 3] = v.w;
  }
  __syncthreads();
#pragma unroll
  for (int i = 0; i < 4; ++i) {
    int n = rr + i * 16;
    half4_t h;
    h[0] = (_Float16)t[c * 4 + 0][n];
    h[1] = (_Float16)t[c * 4 + 1][n];
    h[2] = (_Float16)t[c * 4 + 2][n];
    h[3] = (_Float16)t[c * 4 + 3][n];
    *(half4_t*)(T + (size_t)(by * 64 + n) * DM + bx * 64 + c * 4) = h;
  }
}

// ---------- shared GEMM main loop (BK=64, rule-21 XOR swizzle, R4-verified) -
__device__ __forceinline__ void gemm_loop(const _Float16* __restrict__ A,
                                          const _Float16* __restrict__ Bt,
                                          _Float16* As, _Float16* Bs,
                                          int bm, int bn,
                                          floatx4 (&acc)[4][4]) {
  const int tid = threadIdx.x;
  const int wave = tid >> 6, lane = tid & 63;
  const int wm = wave >> 1, wn = wave & 1;
  const int grow = lane >> 3;           // row within 8-row staging segment
  const int gch  = (lane & 7) ^ grow;   // pre-swizzled source chunk (8 halves)
  const int l16 = lane & 15, lq = lane >> 4;
  const int sw  = l16 & 7;              // row&7 for swizzled reads

  for (int k0 = 0; k0 < DM; k0 += 64) {
    __syncthreads();
#pragma unroll
    for (int s = 0; s < 4; ++s) {
      const int seg = wave * 4 + s;  // 8-row segment of the 128-row tile
      stage16(A + (size_t)(bm + seg * 8 + grow) * DM + k0 + gch * 8,
              As + seg * 512, lane);
      stage16(Bt + (size_t)(bn + seg * 8 + grow) * DM + k0 + gch * 8,
              Bs + seg * 512, lane);
    }
    __syncthreads();
    half8_t af[2][4], bf[2][4];
#pragma unroll
    for (int kk2 = 0; kk2 < 2; ++kk2) {
#pragma unroll
      for (int mi = 0; mi < 4; ++mi)
        af[kk2][mi] = *(const half8_t*)(As + (wm * 64 + mi * 16 + l16) * 64 +
                                        ((kk2 * 4 + lq) ^ sw) * 8);
#pragma unroll
      for (int ni = 0; ni < 4; ++ni)
        bf[kk2][ni] = *(const half8_t*)(Bs + (wn * 64 + ni * 16 + l16) * 64 +
                                        ((kk2 * 4 + lq) ^ sw) * 8);
    }
#pragma unroll
    for (int kk2 = 0; kk2 < 2; ++kk2)
#pragma unroll
      for (int mi = 0; mi < 4; ++mi)
#pragma unroll
        for (int ni = 0; ni < 4; ++ni)
          acc[mi][ni] = __builtin_amdgcn_mfma_f32_16x16x32_f16(
              af[kk2][mi], bf[kk2][ni], acc[mi][ni], 0, 0, 0);
  }
}

// XCD-aware bijective swizzle for a 256-block z-plane (m204; 256 = 8*32)
__device__ __forceinline__ void xcd_decode(int flat, int& bm, int& bn) {
  const int o = (flat & 7) * 32 + (flat >> 3);
  bm = (o >> 3) * 128;
  bn = (o & 7) * 128;
}

// ---------- fused QKV GEMM: LDS-coalesced epilogue (RoPE + w + layout) ------
__global__ __launch_bounds__(256) void gemm_qkv_fused(
    const _Float16* __restrict__ xh, const _Float16* __restrict__ Wt0,
    const _Float16* __restrict__ Wt1, const _Float16* __restrict__ Wt2,
    const float* __restrict__ wre, const float* __restrict__ wim,
    const float* __restrict__ cosT, const float* __restrict__ sinT,
    float* __restrict__ qhO, _Float16* __restrict__ kthO,
    _Float16* __restrict__ vthO) {
  __shared__ __align__(16) _Float16 smem[2 * 128 * 64];  // 32 KB
  _Float16* As = smem;
  _Float16* Bs = smem + 128 * 64;
  const int z = blockIdx.z;
  const _Float16* Bt = (z == 0) ? Wt0 : (z == 1) ? Wt1 : Wt2;
  int bm, bn;
  xcd_decode(blockIdx.x, bm, bn);
  floatx4 acc[4][4] = {};
  gemm_loop(xh, Bt, As, Bs, bm, bn, acc);
  __syncthreads();  // all ds_reads of the last tile done before smem reuse

  float* cbuf = (float*)smem;  // [32][CSTRIDE] = 16896 B, fits in 32 KB
  const int tid = threadIdx.x;
  const int wave = tid >> 6, lane = tid & 63;
  const int wm = wave >> 1, wn = wave & 1;
  const int l16 = lane & 15, lq = lane >> 4;

  // read-phase mapping: 2 heads x 32 rows x 4 kk-octets
  const int h2 = tid >> 7, t7 = tid & 127;
  const int rl = t7 >> 2, q4 = t7 & 3;
  const int hh = (bn >> 6) + h2;
  const int row_nom = bm + (rl >> 4) * 64 + (rl & 15);  // + mi*16 in loop
  const int kk0 = q4 * 8;

#pragma unroll
  for (int mi = 0; mi < 4; ++mi) {
    // scatter: 32 rows x 128 cols of C, f32
#pragma unroll
    for (int ni = 0; ni < 4; ++ni)
#pragma unroll
      for (int r = 0; r < 4; ++r)
        cbuf[(wm * 16 + lq * 4 + r) * CSTRIDE + wn * 64 + ni * 16 + l16] =
            acc[mi][ni][r];
    __syncthreads();

    const int row = row_nom + mi * 16;
    const int b = row >> 11, n = row & (N_SEQ - 1);
    const float* crow = cbuf + rl * CSTRIDE + h2 * 64;
    const size_t base = ((size_t)((b * H_HEADS + hh) * N_SEQ + n)) * DH;

    if (z == 2) {
      const int d0 = q4 * 16;
      half8_t o0, o1;
#pragma unroll
      for (int j = 0; j < 8; ++j) {
        o0[j] = (_Float16)crow[d0 + j];
        o1[j] = (_Float16)crow[d0 + 8 + j];
      }
      *(half8_t*)(vthO + base + d0) = o0;
      *(half8_t*)(vthO + base + d0 + 8) = o1;
    } else if (z == 1) {
      const float sj = 0.125f * sqrtf(1.0f + (float)n);
      half8_t ore, oim;
#pragma unroll
      for (int j = 0; j < 8; ++j) {
        const int kk = kk0 + j;
        const float re = crow[2 * kk], im = crow[2 * kk + 1];
        const float cp = cosT[n * 32 + kk], sp = sinT[n * 32 + kk];
        ore[j] = (_Float16)((cp * re + sp * im) * sj);
        oim[j] = (_Float16)((cp * im - sp * re) * sj);
      }
      *(half8_t*)(kthO + base + kk0) = ore;
      *(half8_t*)(kthO + base + 32 + kk0) = oim;
    } else {
      float ore[8], oim[8];
#pragma unroll
      for (int j = 0; j < 8; ++j) {
        const int kk = kk0 + j;
        const float re = crow[2 * kk], im = crow[2 * kk + 1];
        const float cp = cosT[n * 32 + kk], sp = sinT[n * 32 + kk];
        const float t_re = cp * re + sp * im;
        const float t_im = cp * im - sp * re;
        const float wr = wre[kk], wi = wim[kk];
        ore[j] = wr * t_re - wi * t_im;
        oim[j] = wr * t_im + wi * t_re;
      }
      float4 v0 = {ore[0], ore[1], ore[2], ore[3]};
      float4 v1 = {ore[4], ore[5], ore[6], ore[7]};
      float4 v2 = {oim[0], oim[1], oim[2], oim[3]};
      float4 v3 = {oim[4], oim[5], oim[6], oim[7]};
      *(float4*)(qhO + base + kk0) = v0;
      *(float4*)(qhO + base + kk0 + 4) = v1;
      *(float4*)(qhO + base + 32 + kk0) = v2;
      *(float4*)(qhO + base + 32 + kk0 + 4) = v3;
    }
    if (mi < 3) __syncthreads();
  }
}

// ---------- output GEMM (plain epilogue) ----------
__global__ __launch_bounds__(256) void gemm_out_mfma(
    const _Float16* __restrict__ A, const _Float16* __restrict__ Bt,
    float* __restrict__ C) {
  __shared__ _Float16 As[128 * 64];
  __shared__ _Float16 Bs[128 * 64];
  int bm, bn;
  xcd_decode(blockIdx.x, bm, bn);
  floatx4 acc[4][4] = {};
  gemm_loop(A, Bt, As, Bs, bm, bn, acc);
  const int tid = threadIdx.x;
  const int wave = tid >> 6, lane = tid & 63;
  const int wm = wave >> 1, wn = wave & 1;
  const int l16 = lane & 15, lq = lane >> 4;
#pragma unroll
  for (int mi = 0; mi < 4; ++mi)
#pragma unroll
    for (int ni = 0; ni < 4; ++ni) {
      const int col = bn + wn * 64 + ni * 16 + l16;
#pragma unroll
      for (int r = 0; r < 4; ++r) {
        const int row = bm + wm * 64 + mi * 16 + lq * 4 + r;
        C[(size_t)row * DM + col] = acc[mi][ni][r];
      }
    }
}

// ---------- attention: EXACT R9 kernel (measured 248 us) --------------------
// No K staging (direct global->VGPR fragments, barrier-free pass A).
// PV gather: dense per-row serial loop, unroll 4 — DO NOT guard-interleave
// rows (R2/R10 both regressed ~2x from the branchy dual-chain form).
__global__ __launch_bounds__(512, 4) void attn_kernel(
    const float* __restrict__ qh, const _Float16* __restrict__ kth,
    const _Float16* __restrict__ vth, _Float16* __restrict__ oh) {
  __shared__ unsigned hist[TQ][128];                  // 8192 B packed 16-bit
  __shared__ unsigned final_[TQ][FCAP];               // 12288 B (p<<16)|j
  __shared__ float mredw[8][TQ];                      // 512 B
  __shared__ float rowm[TQ], rowsum[TQ];
  __shared__ unsigned cnt2[TQ], tkA[TQ];
  __shared__ int sh_b[TQ], sh_k[TQ];

  const int tile = gridDim.x - 1 - blockIdx.x;  // heavy blocks first
  const int bh   = blockIdx.y;                  // 0..31
  const int i0   = tile * TQ;
  const int tid  = threadIdx.x;
  const int wv = tid >> 6, lane = tid & 63;
  const int l16 = lane & 15, lq = lane >> 4;
  const int jbase = wv * 16 + l16;              // col within a 128-wide tile

  const _Float16* kbase = kth + (size_t)bh * N_SEQ * DH;
  const _Float16* vbase = vth + (size_t)bh * N_SEQ * DH;
  // per-lane K fragment base: row jbase, halves [lq*8..lq*8+8) and +32
  const _Float16* kfrag = kbase + (size_t)jbase * DH + lq * 8;

  // ---- init ----
#pragma unroll
  for (int u = 0; u < 4; ++u) ((unsigned*)hist)[u * 512 + tid] = 0;
  if (tid < TQ) { cnt2[tid] = 0; rowsum[tid] = 0.f; }

  // ---- A-fragment: row m=l16 -> q row i0+l16, k=lq*8+j (K=64 via 2 mfma) ----
  half8_t af0, af1;
  {
    const float* qrow = qh + ((size_t)(bh * N_SEQ + i0 + l16)) * DH;
    const float rs = rsqrtf(1.0f + (float)(i0 + l16));
    float4 a0 = *(const float4*)(qrow + lq * 8);
    float4 a1 = *(const float4*)(qrow + lq * 8 + 4);
    float4 b0 = *(const float4*)(qrow + 32 + lq * 8);
    float4 b1 = *(const float4*)(qrow + 32 + lq * 8 + 4);
    af0[0] = (_Float16)(a0.x * rs); af0[1] = (_Float16)(a0.y * rs);
    af0[2] = (_Float16)(a0.z * rs); af0[3] = (_Float16)(a0.w * rs);
    af0[4] = (_Float16)(a1.x * rs); af0[5] = (_Float16)(a1.y * rs);
    af0[6] = (_Float16)(a1.z * rs); af0[7] = (_Float16)(a1.w * rs);
    af1[0] = (_Float16)(b0.x * rs); af1[1] = (_Float16)(b0.y * rs);
    af1[2] = (_Float16)(b0.z * rs); af1[3] = (_Float16)(b0.w * rs);
    af1[4] = (_Float16)(b1.x * rs); af1[5] = (_Float16)(b1.y * rs);
    af1[6] = (_Float16)(b1.z * rs); af1[7] = (_Float16)(b1.w * rs);
  }

  const int ntile = (i0 + TQ + KT - 1) / KT;  // uniform across block, <= 16

  ushort4_t scr[NTMAX];  // 64 fp16 scores, static indexing only
  float mx[4] = {-INFINITY, -INFINITY, -INFINITY, -INFINITY};

  __syncthreads();  // hist zero-init visible to all before pass A atomics

  // ---- pass A: barrier-free MFMA sweep. scores -> regs, hist, row max ----
#pragma unroll
  for (int t = 0; t < NTMAX; ++t) {
    if (t < ntile) {  // block-uniform
      const _Float16* kp = kfrag + (size_t)t * KT * DH;
      half8_t bf0 = *(const half8_t*)kp;
      half8_t bf1 = *(const half8_t*)(kp + 32);
      floatx4 acc = {};
      acc = __builtin_amdgcn_mfma_f32_16x16x32_f16(af0, bf0, acc, 0, 0, 0);
      acc = __builtin_amdgcn_mfma_f32_16x16x32_f16(af1, bf1, acc, 0, 0, 0);
      const int jc = t * KT + jbase;
      ushort4_t s4;
#pragma unroll
      for (int r = 0; r < 4; ++r) {
        float sc = acc[r];
        s4[r] = h2us((_Float16)sc);
        if (jc <= i0 + lq * 4 + r) {
          mx[r] = fmaxf(mx[r], sc);
          unsigned hb = okey16(s4[r]) >> 8;
          atomicAdd(&hist[lq * 4 + r][hb >> 1], 1u << ((hb & 1) * 16));
        }
      }
      scr[t] = s4;
    }
  }

  // ---- row max: reduce over 16-lane group, then over 8 waves ----
#pragma unroll
  for (int g = 1; g <= 8; g <<= 1)
#pragma unroll
    for (int r = 0; r < 4; ++r) mx[r] = fmaxf(mx[r], __shfl_xor(mx[r], g));
  if (l16 == 0)
#pragma unroll
    for (int r = 0; r < 4; ++r) mredw[wv][lq * 4 + r] = mx[r];
  __syncthreads();
  if (tid < TQ) {
    float m = mredw[0][tid];
#pragma unroll
    for (int w = 1; w < 8; ++w) m = fmaxf(m, mredw[w][tid]);
    rowm[tid] = m;
  }

  // ---- parallel hi-byte select: 32 threads/row, 8 bins/thread, suffix scan -
  const int srow = tid >> 5, ts = tid & 31;
  {
    const int L = i0 + srow + 1;
    if (L > TOPK) {
      const unsigned* hrow = hist[srow];
      const int base_u = 124 - 4 * ts;  // bins 255-8ts .. 248-8ts descending
      unsigned h0 = hrow[base_u + 0], h1 = hrow[base_u + 1];
      unsigned h2 = hrow[base_u + 2], h3 = hrow[base_u + 3];
      int c[8] = {(int)(h3 >> 16), (int)(h3 & 0xffffu),
                  (int)(h2 >> 16), (int)(h2 & 0xffffu),
                  (int)(h1 >> 16), (int)(h1 & 0xffffu),
                  (int)(h0 >> 16), (int)(h0 & 0xffffu)};
      int ssum = 0;
#pragma unroll
      for (int k2 = 0; k2 < 8; ++k2) ssum += c[k2];
      int inc = ssum;
#pragma unroll
      for (int d = 1; d < 32; d <<= 1) {
        int o = __shfl_up(inc, d, 32);
        if (ts >= d) inc += o;
      }
      const int excl = inc - ssum;
      if (excl < TOPK && TOPK <= inc) {  // crossing lives in my 8 bins
        int cum = excl, k2 = 0;
#pragma unroll
        for (; k2 < 8; ++k2) {
          if (cum + c[k2] >= TOPK) break;
          cum += c[k2];
        }
        sh_b[srow] = 255 - 8 * ts - k2;
        sh_k[srow] = TOPK - cum;
      }
    } else if (ts == 0) {
      sh_b[srow] = 256;  // no hi-byte matches -> pass B no-op for this row
      sh_k[srow] = 0;
      tkA[srow] = 0;     // all valid entries survive
    }
  }
  __syncthreads();
#pragma unroll
  for (int u = 0; u < 4; ++u) ((unsigned*)hist)[u * 512 + tid] = 0;
  int bh4[4];
#pragma unroll
  for (int r = 0; r < 4; ++r) bh4[r] = sh_b[lq * 4 + r];
  __syncthreads();

  // ---- pass B: register scan -> lo-byte hist of the threshold bucket ----
#pragma unroll
  for (int t = 0; t < NTMAX; ++t) {
    if (t < ntile) {
      const int jc = t * KT + jbase;
      ushort4_t s4 = scr[t];
#pragma unroll
      for (int r = 0; r < 4; ++r) {
        if (jc <= i0 + lq * 4 + r) {
          unsigned key = okey16(s4[r]);
          if ((int)(key >> 8) == bh4[r]) {
            unsigned lb = key & 255u;
            atomicAdd(&hist[lq * 4 + r][lb >> 1], 1u << ((lb & 1) * 16));
          }
        }
      }
    }
  }
  __syncthreads();

  // ---- parallel lo-byte select -> exact fp16 threshold key ----
  {
    const int L = i0 + srow + 1;
    if (L > TOPK) {
      const int krem = sh_k[srow];
      const unsigned* hrow = hist[srow];
      const int base_u = 124 - 4 * ts;
      unsigned h0 = hrow[base_u + 0], h1 = hrow[base_u + 1];
      unsigned h2 = hrow[base_u + 2], h3 = hrow[base_u + 3];
      int c[8] = {(int)(h3 >> 16), (int)(h3 & 0xffffu),
                  (int)(h2 >> 16), (int)(h2 & 0xffffu),
                  (int)(h1 >> 16), (int)(h1 & 0xffffu),
                  (int)(h0 >> 16), (int)(h0 & 0xffffu)};
      int ssum = 0;
#pragma unroll
      for (int k2 = 0; k2 < 8; ++k2) ssum += c[k2];
      int inc = ssum;
#pragma unroll
      for (int d = 1; d < 32; d <<= 1) {
        int o = __shfl_up(inc, d, 32);
        if (ts >= d) inc += o;
      }
      const int excl = inc - ssum;
      if (excl < krem && krem <= inc) {
        int cum = excl, k2 = 0;
#pragma unroll
        for (; k2 < 8; ++k2) {
          if (cum + c[k2] >= krem) break;
          cum += c[k2];
        }
        tkA[srow] = ((unsigned)sh_b[srow] << 8) | (unsigned)(255 - 8 * ts - k2);
      }
    }
  }
  __syncthreads();

  // ---- pass C: register scan -> survivors + exp, direct append ----
  unsigned tk4[4]; float m4[4];
#pragma unroll
  for (int r = 0; r < 4; ++r) {
    tk4[r] = tkA[lq * 4 + r];
    m4[r]  = rowm[lq * 4 + r];
  }
  float lsum[4] = {0.f, 0.f, 0.f, 0.f};
#pragma unroll
  for (int t = 0; t < NTMAX; ++t) {
    if (t < ntile) {
      const int jc = t * KT + jbase;
      ushort4_t s4 = scr[t];
#pragma unroll
      for (int r = 0; r < 4; ++r) {
        if (jc <= i0 + lq * 4 + r) {
          unsigned short us = s4[r];
          if (okey16(us) >= tk4[r]) {
            float p = __expf((float)us2h(us) - m4[r]);
            lsum[r] += p;
            unsigned pos = atomicAdd(&cnt2[lq * 4 + r], 1u);
            if (pos < FCAP)
              final_[lq * 4 + r][pos] =
                  ((unsigned)h2us((_Float16)p) << 16) | (unsigned)jc;
          }
        }
      }
    }
  }
#pragma unroll
  for (int g = 1; g <= 8; g <<= 1)
#pragma unroll
    for (int r = 0; r < 4; ++r) lsum[r] += __shfl_xor(lsum[r], g);
  if (l16 == 0)
#pragma unroll
    for (int r = 0; r < 4; ++r) atomicAdd(&rowsum[lq * 4 + r], lsum[r]);
  __syncthreads();

  // ---- sparse p @ V, one wave per row (p already exp'd, fp16 in final_) ----
  for (int rr = wv; rr < TQ; rr += 8) {
    const int nfin = (int)min(cnt2[rr], (unsigned)FCAP);
    const float inv = 1.0f / rowsum[rr];
    float acc = 0.f;
#pragma unroll 4
    for (int s = 0; s < nfin; ++s) {
      unsigned e = final_[rr][s];
      const int jj = (int)(e & 0xffffu);
      const float p = (float)us2h((unsigned short)(e >> 16));
      acc += p * (float)vbase[(size_t)jj * DH + lane];
    }
    const int b = bh >> 4, h = bh & 15;
    const int i = i0 + rr;
    oh[((size_t)(b * N_SEQ + i)) * DM + h * DH + lane] = (_Float16)(acc * inv);
  }
}

// ---------- launch ----------
extern "C" void kernel_launch(void* const* d_in, const int* in_sizes, int n_in,
                              void* d_out, int out_size, void* d_ws, size_t ws_size,
                              hipStream_t stream) {
  const float* x  = (const float*)d_in[0];
  const float* Wq = (const float*)d_in[1];
  const float* Wk = (const float*)d_in[2];
  const float* Wv = (const float*)d_in[3];
  const float* Wo = (const float*)d_in[4];
  float* out = (float*)d_out;
  char* ws = (char*)d_ws;

  const size_t MAT = (size_t)B_SZ * N_SEQ * DM;  // 4,194,304 elements
  const size_t WSZ = (size_t)DM * DM;            // 1,048,576

  float*    qh   = (float*)ws;                       ws += MAT * 4;   // 16 MB
  _Float16* xh   = (_Float16*)ws;                    ws += MAT * 2;   // 8 MB
  _Float16* kth  = (_Float16*)ws;                    ws += MAT * 2;
  _Float16* vth  = (_Float16*)ws;                    ws += MAT * 2;
  _Float16* Wt0  = (_Float16*)ws;                    ws += WSZ * 2;
  _Float16* Wt1  = (_Float16*)ws;                    ws += WSZ * 2;
  _Float16* Wt2  = (_Float16*)ws;                    ws += WSZ * 2;
  _Float16* Wt3  = (_Float16*)ws;                    ws += WSZ * 2;
  float*    wre  = (float*)ws;                       ws += KC * 4;
  float*    wim  = (float*)ws;                       ws += KC * 4;
  float*    cosT = (float*)ws;                       ws += (size_t)N_SEQ * KC * 4;
  float*    sinT = (float*)ws;                       ws += (size_t)N_SEQ * KC * 4;
  _Float16* oh   = xh;  // xh dead after QKV GEMM; reuse for attn output

  setup_kernel<<<4096 + 256 + 1, 256, 0, stream>>>(x, xh, cosT, sinT, wre, wim);
  transpose_cast<<<dim3(16, 16, 4), 256, 0, stream>>>(Wq, Wk, Wv, Wo,
                                                      Wt0, Wt1, Wt2, Wt3);
  gemm_qkv_fused<<<dim3(256, 1, 3), 256, 0, stream>>>(
      xh, Wt0, Wt1, Wt2, wre, wim, cosT, sinT, qh, kth, vth);
  attn_kernel<<<dim3(N_SEQ / TQ, B_SZ * H_HEADS), 512, 0, stream>>>(
      qh, kth, vth, oh);
  gemm_out_mfma<<<dim3(256), 256, 0, stream>>>(oh, Wt3, out);
}

// Round 12
// 356.590 us; speedup vs baseline: 1.5809x; 1.0896x over previous
//
#include <hip/hip_runtime.h>
#include <math.h>

#define B_SZ 2
#define N_SEQ 2048
#define DM 1024
#define H_HEADS 16
#define DH 64
#define KC 32
#define TOPK 100
#define TQ 16
#define KT 128
#define NTMAX 16
#define FCAP 192
#define CSTRIDE 132

typedef _Float16 half2_t __attribute__((ext_vector_type(2)));
typedef _Float16 half4_t __attribute__((ext_vector_type(4)));
typedef _Float16 half8_t __attribute__((ext_vector_type(8)));
typedef float floatx4 __attribute__((ext_vector_type(4)));
typedef unsigned short ushort4_t __attribute__((ext_vector_type(4)));

// ---------- helpers ----------
__device__ __forceinline__ unsigned short h2us(_Float16 h) {
  unsigned short u; __builtin_memcpy(&u, &h, 2); return u;
}
__device__ __forceinline__ _Float16 us2h(unsigned short u) {
  _Float16 h; __builtin_memcpy(&h, &u, 2); return h;
}
__device__ __forceinline__ unsigned okey16(unsigned short us) {
  return (us & 0x8000u) ? (unsigned)(unsigned short)~us
                        : (unsigned)(us | 0x8000u);
}

// async global->LDS, 16 B per lane; lds_base must be wave-uniform
__device__ __forceinline__ void stage16(const _Float16* g, _Float16* lds_base,
                                        int lane) {
#if __has_builtin(__builtin_amdgcn_global_load_lds)
  __builtin_amdgcn_global_load_lds(
      (const __attribute__((address_space(1))) void*)g,
      (__attribute__((address_space(3))) void*)lds_base, 16, 0, 0);
#else
  *(half8_t*)(lds_base + lane * 8) = *(const half8_t*)g;
#endif
}

// ---------- merged setup: cast_x (4096 blk) + rope (256 blk) + const (1 blk)
__global__ __launch_bounds__(256) void setup_kernel(
    const float* __restrict__ x, _Float16* __restrict__ xh,
    float* __restrict__ cosT, float* __restrict__ sinT,
    float* __restrict__ wre, float* __restrict__ wim) {
  const int bi = blockIdx.x;
  if (bi < 4096) {
    // cast x fp32 -> fp16
    int idx = bi * 256 + threadIdx.x;
    float4 v = ((const float4*)x)[idx];
    half4_t h;
    h[0] = (_Float16)v.x; h[1] = (_Float16)v.y;
    h[2] = (_Float16)v.z; h[3] = (_Float16)v.w;
    ((half4_t*)xh)[idx] = h;
  } else if (bi < 4096 + 256) {
    // RoPE tables (f32 math; err far under fp16 quantization downstream)
    int idx = (bi - 4096) * 256 + threadIdx.x;  // 65536 = 2048*32
    int kk = idx & 31, n = idx >> 5;
    float f = -(float)kk * (13.2877123795494f / 32.0f);
    float inv_freq = exp2f(f);
    float ph = (float)n * inv_freq;
    cosT[idx] = cosf(ph);
    sinT[idx] = sinf(ph);
  } else {
    // Riemann-zero weights (32 active threads)
    __shared__ double g0s;
    const int k = threadIdx.x;
    const double PI = 3.14159265358979323846;
    const double E_ = 2.71828182845904523536;
    double t = 0.0;
    if (k < 32) {
      double n = (double)(k + 1);
      t = 10.0 + 6.0 * n;
      for (int it = 0; it < 16; ++it) {
        double f  = t / (2.0 * PI) * log(t / (2.0 * PI * E_)) - (n - 0.875);
        double fp = log(t / (2.0 * PI)) / (2.0 * PI);
        t = t - f / fp;
      }
      if (k == 0) g0s = t;
    }
    __syncthreads();
    if (k < 32) {
      double g = t / g0s;
      double denom = 0.25 + g * g;
      wre[k] = (float)(0.5 / denom);
      wim[k] = (float)(-g / denom);
    }
  }
}

// ---------- transpose-cast W (fp32 [k][n]) -> Wt (fp16 [n][k]) ----------
__global__ __launch_bounds__(256) void transpose_cast(
    const float* __restrict__ W0, const float* __restrict__ W1,
    const float* __restrict__ W2, const float* __restrict__ W3,
    _Float16* __restrict__ T0, _Float16* __restrict__ T1,
    _Float16* __restrict__ T2, _Float16* __restrict__ T3) {
  __shared__ float t[64][65];
  const float* W; _Float16* T;
  switch (blockIdx.z) {
    case 0: W = W0; T = T0; break;
    case 1: W = W1; T = T1; break;
    case 2: W = W2; T = T2; break;
    default: W = W3; T = T3; break;
  }
  const int bx = blockIdx.x;  // k block
  const int by = blockIdx.y;  // n block
  const int tid = threadIdx.x;
  const int c = tid & 15, rr = tid >> 4;
#pragma unroll
  for (int i = 0; i < 4; ++i) {
    int k = rr + i * 16;
    float4 v = *(const float4*)(W + (size_t)(bx * 64 + k) * DM + by * 64 + c * 4);
    t[k][c * 4 + 0] = v.x; t[k][c * 4 + 1] = v.y;
    t[k][c * 4 + 2] = v.z; t[k][c * 4 + 3] = v.w;
  }
  __syncthreads();
#pragma unroll
  for (int i = 0; i < 4; ++i) {
    int n = rr + i * 16;
    half4_t h;
    h[0] = (_Float16)t[c * 4 + 0][n];
    h[1] = (_Float16)t[c * 4 + 1][n];
    h[2] = (_Float16)t[c * 4 + 2][n];
    h[3] = (_Float16)t[c * 4 + 3][n];
    *(half4_t*)(T + (size_t)(by * 64 + n) * DM + bx * 64 + c * 4) = h;
  }
}

// ---------- shared GEMM main loop (BK=64, rule-21 XOR swizzle, R4-verified) -
__device__ __forceinline__ void gemm_loop(const _Float16* __restrict__ A,
                                          const _Float16* __restrict__ Bt,
                                          _Float16* As, _Float16* Bs,
                                          int bm, int bn,
                                          floatx4 (&acc)[4][4]) {
  const int tid = threadIdx.x;
  const int wave = tid >> 6, lane = tid & 63;
  const int wm = wave >> 1, wn = wave & 1;
  const int grow = lane >> 3;           // row within 8-row staging segment
  const int gch  = (lane & 7) ^ grow;   // pre-swizzled source chunk (8 halves)
  const int l16 = lane & 15, lq = lane >> 4;
  const int sw  = l16 & 7;              // row&7 for swizzled reads

  for (int k0 = 0; k0 < DM; k0 += 64) {
    __syncthreads();
#pragma unroll
    for (int s = 0; s < 4; ++s) {
      const int seg = wave * 4 + s;  // 8-row segment of the 128-row tile
      stage16(A + (size_t)(bm + seg * 8 + grow) * DM + k0 + gch * 8,
              As + seg * 512, lane);
      stage16(Bt + (size_t)(bn + seg * 8 + grow) * DM + k0 + gch * 8,
              Bs + seg * 512, lane);
    }
    __syncthreads();
    half8_t af[2][4], bf[2][4];
#pragma unroll
    for (int kk2 = 0; kk2 < 2; ++kk2) {
#pragma unroll
      for (int mi = 0; mi < 4; ++mi)
        af[kk2][mi] = *(const half8_t*)(As + (wm * 64 + mi * 16 + l16) * 64 +
                                        ((kk2 * 4 + lq) ^ sw) * 8);
#pragma unroll
      for (int ni = 0; ni < 4; ++ni)
        bf[kk2][ni] = *(const half8_t*)(Bs + (wn * 64 + ni * 16 + l16) * 64 +
                                        ((kk2 * 4 + lq) ^ sw) * 8);
    }
#pragma unroll
    for (int kk2 = 0; kk2 < 2; ++kk2)
#pragma unroll
      for (int mi = 0; mi < 4; ++mi)
#pragma unroll
        for (int ni = 0; ni < 4; ++ni)
          acc[mi][ni] = __builtin_amdgcn_mfma_f32_16x16x32_f16(
              af[kk2][mi], bf[kk2][ni], acc[mi][ni], 0, 0, 0);
  }
}

// XCD-aware bijective swizzle for a 256-block z-plane (m204; 256 = 8*32)
__device__ __forceinline__ void xcd_decode(int flat, int& bm, int& bn) {
  const int o = (flat & 7) * 32 + (flat >> 3);
  bm = (o >> 3) * 128;
  bn = (o & 7) * 128;
}

// ---------- fused QKV GEMM: LDS-coalesced epilogue (RoPE + w + layout) ------
__global__ __launch_bounds__(256) void gemm_qkv_fused(
    const _Float16* __restrict__ xh, const _Float16* __restrict__ Wt0,
    const _Float16* __restrict__ Wt1, const _Float16* __restrict__ Wt2,
    const float* __restrict__ wre, const float* __restrict__ wim,
    const float* __restrict__ cosT, const float* __restrict__ sinT,
    float* __restrict__ qhO, _Float16* __restrict__ kthO,
    _Float16* __restrict__ vthO) {
  __shared__ __align__(16) _Float16 smem[2 * 128 * 64];  // 32 KB
  _Float16* As = smem;
  _Float16* Bs = smem + 128 * 64;
  const int z = blockIdx.z;
  const _Float16* Bt = (z == 0) ? Wt0 : (z == 1) ? Wt1 : Wt2;
  int bm, bn;
  xcd_decode(blockIdx.x, bm, bn);
  floatx4 acc[4][4] = {};
  gemm_loop(xh, Bt, As, Bs, bm, bn, acc);
  __syncthreads();  // all ds_reads of the last tile done before smem reuse

  float* cbuf = (float*)smem;  // [32][CSTRIDE] = 16896 B, fits in 32 KB
  const int tid = threadIdx.x;
  const int wave = tid >> 6, lane = tid & 63;
  const int wm = wave >> 1, wn = wave & 1;
  const int l16 = lane & 15, lq = lane >> 4;

  // read-phase mapping: 2 heads x 32 rows x 4 kk-octets
  const int h2 = tid >> 7, t7 = tid & 127;
  const int rl = t7 >> 2, q4 = t7 & 3;
  const int hh = (bn >> 6) + h2;
  const int row_nom = bm + (rl >> 4) * 64 + (rl & 15);  // + mi*16 in loop
  const int kk0 = q4 * 8;

#pragma unroll
  for (int mi = 0; mi < 4; ++mi) {
    // scatter: 32 rows x 128 cols of C, f32
#pragma unroll
    for (int ni = 0; ni < 4; ++ni)
#pragma unroll
      for (int r = 0; r < 4; ++r)
        cbuf[(wm * 16 + lq * 4 + r) * CSTRIDE + wn * 64 + ni * 16 + l16] =
            acc[mi][ni][r];
    __syncthreads();

    const int row = row_nom + mi * 16;
    const int b = row >> 11, n = row & (N_SEQ - 1);
    const float* crow = cbuf + rl * CSTRIDE + h2 * 64;
    const size_t base = ((size_t)((b * H_HEADS + hh) * N_SEQ + n)) * DH;

    if (z == 2) {
      const int d0 = q4 * 16;
      half8_t o0, o1;
#pragma unroll
      for (int j = 0; j < 8; ++j) {
        o0[j] = (_Float16)crow[d0 + j];
        o1[j] = (_Float16)crow[d0 + 8 + j];
      }
      *(half8_t*)(vthO + base + d0) = o0;
      *(half8_t*)(vthO + base + d0 + 8) = o1;
    } else if (z == 1) {
      const float sj = 0.125f * sqrtf(1.0f + (float)n);
      half8_t ore, oim;
#pragma unroll
      for (int j = 0; j < 8; ++j) {
        const int kk = kk0 + j;
        const float re = crow[2 * kk], im = crow[2 * kk + 1];
        const float cp = cosT[n * 32 + kk], sp = sinT[n * 32 + kk];
        ore[j] = (_Float16)((cp * re + sp * im) * sj);
        oim[j] = (_Float16)((cp * im - sp * re) * sj);
      }
      *(half8_t*)(kthO + base + kk0) = ore;
      *(half8_t*)(kthO + base + 32 + kk0) = oim;
    } else {
      float ore[8], oim[8];
#pragma unroll
      for (int j = 0; j < 8; ++j) {
        const int kk = kk0 + j;
        const float re = crow[2 * kk], im = crow[2 * kk + 1];
        const float cp = cosT[n * 32 + kk], sp = sinT[n * 32 + kk];
        const float t_re = cp * re + sp * im;
        const float t_im = cp * im - sp * re;
        const float wr = wre[kk], wi = wim[kk];
        ore[j] = wr * t_re - wi * t_im;
        oim[j] = wr * t_im + wi * t_re;
      }
      float4 v0 = {ore[0], ore[1], ore[2], ore[3]};
      float4 v1 = {ore[4], ore[5], ore[6], ore[7]};
      float4 v2 = {oim[0], oim[1], oim[2], oim[3]};
      float4 v3 = {oim[4], oim[5], oim[6], oim[7]};
      *(float4*)(qhO + base + kk0) = v0;
      *(float4*)(qhO + base + kk0 + 4) = v1;
      *(float4*)(qhO + base + 32 + kk0) = v2;
      *(float4*)(qhO + base + 32 + kk0 + 4) = v3;
    }
    if (mi < 3) __syncthreads();
  }
}

// ---------- output GEMM (plain epilogue) ----------
__global__ __launch_bounds__(256) void gemm_out_mfma(
    const _Float16* __restrict__ A, const _Float16* __restrict__ Bt,
    float* __restrict__ C) {
  __shared__ _Float16 As[128 * 64];
  __shared__ _Float16 Bs[128 * 64];
  int bm, bn;
  xcd_decode(blockIdx.x, bm, bn);
  floatx4 acc[4][4] = {};
  gemm_loop(A, Bt, As, Bs, bm, bn, acc);
  const int tid = threadIdx.x;
  const int wave = tid >> 6, lane = tid & 63;
  const int wm = wave >> 1, wn = wave & 1;
  const int l16 = lane & 15, lq = lane >> 4;
#pragma unroll
  for (int mi = 0; mi < 4; ++mi)
#pragma unroll
    for (int ni = 0; ni < 4; ++ni) {
      const int col = bn + wn * 64 + ni * 16 + l16;
#pragma unroll
      for (int r = 0; r < 4; ++r) {
        const int row = bm + wm * 64 + mi * 16 + lq * 4 + r;
        C[(size_t)row * DM + col] = acc[mi][ni][r];
      }
    }
}

// ---------- attention: R9 structure; PV = padded half-wave split ------------
// Pass A: no K staging, barrier-free (R9, verified 248 us).
// PV: zero-pad shorter list of each row pair to pair max, then DENSE
// branchless loop with lanes 0-31 on row 2wv, lanes 32-63 on row 2wv+1
// (2 dims/lane, half2 loads). Serial chain = max(n0,n1) vs n0+n1.
// NOTE: no guarded/branchy interleave (R2/R10 regressed 2x from that).
__global__ __launch_bounds__(512, 4) void attn_kernel(
    const float* __restrict__ qh, const _Float16* __restrict__ kth,
    const _Float16* __restrict__ vth, _Float16* __restrict__ oh) {
  __shared__ unsigned hist[TQ][128];                  // 8192 B packed 16-bit
  __shared__ unsigned final_[TQ][FCAP];               // 12288 B (p<<16)|j
  __shared__ float mredw[8][TQ];                      // 512 B
  __shared__ float rowm[TQ], rowsum[TQ];
  __shared__ unsigned cnt2[TQ], tkA[TQ];
  __shared__ int sh_b[TQ], sh_k[TQ];

  const int tile = gridDim.x - 1 - blockIdx.x;  // heavy blocks first
  const int bh   = blockIdx.y;                  // 0..31
  const int i0   = tile * TQ;
  const int tid  = threadIdx.x;
  const int wv = tid >> 6, lane = tid & 63;
  const int l16 = lane & 15, lq = lane >> 4;
  const int jbase = wv * 16 + l16;              // col within a 128-wide tile

  const _Float16* kbase = kth + (size_t)bh * N_SEQ * DH;
  const _Float16* vbase = vth + (size_t)bh * N_SEQ * DH;
  // per-lane K fragment base: row jbase, halves [lq*8..lq*8+8) and +32
  const _Float16* kfrag = kbase + (size_t)jbase * DH + lq * 8;

  // ---- init ----
#pragma unroll
  for (int u = 0; u < 4; ++u) ((unsigned*)hist)[u * 512 + tid] = 0;
  if (tid < TQ) { cnt2[tid] = 0; rowsum[tid] = 0.f; }

  // ---- A-fragment: row m=l16 -> q row i0+l16, k=lq*8+j (K=64 via 2 mfma) ----
  half8_t af0, af1;
  {
    const float* qrow = qh + ((size_t)(bh * N_SEQ + i0 + l16)) * DH;
    const float rs = rsqrtf(1.0f + (float)(i0 + l16));
    float4 a0 = *(const float4*)(qrow + lq * 8);
    float4 a1 = *(const float4*)(qrow + lq * 8 + 4);
    float4 b0 = *(const float4*)(qrow + 32 + lq * 8);
    float4 b1 = *(const float4*)(qrow + 32 + lq * 8 + 4);
    af0[0] = (_Float16)(a0.x * rs); af0[1] = (_Float16)(a0.y * rs);
    af0[2] = (_Float16)(a0.z * rs); af0[3] = (_Float16)(a0.w * rs);
    af0[4] = (_Float16)(a1.x * rs); af0[5] = (_Float16)(a1.y * rs);
    af0[6] = (_Float16)(a1.z * rs); af0[7] = (_Float16)(a1.w * rs);
    af1[0] = (_Float16)(b0.x * rs); af1[1] = (_Float16)(b0.y * rs);
    af1[2] = (_Float16)(b0.z * rs); af1[3] = (_Float16)(b0.w * rs);
    af1[4] = (_Float16)(b1.x * rs); af1[5] = (_Float16)(b1.y * rs);
    af1[6] = (_Float16)(b1.z * rs); af1[7] = (_Float16)(b1.w * rs);
  }

  const int ntile = (i0 + TQ + KT - 1) / KT;  // uniform across block, <= 16

  ushort4_t scr[NTMAX];  // 64 fp16 scores, static indexing only
  float mx[4] = {-INFINITY, -INFINITY, -INFINITY, -INFINITY};

  __syncthreads();  // hist zero-init visible to all before pass A atomics

  // ---- pass A: barrier-free MFMA sweep. scores -> regs, hist, row max ----
#pragma unroll
  for (int t = 0; t < NTMAX; ++t) {
    if (t < ntile) {  // block-uniform
      const _Float16* kp = kfrag + (size_t)t * KT * DH;
      half8_t bf0 = *(const half8_t*)kp;
      half8_t bf1 = *(const half8_t*)(kp + 32);
      floatx4 acc = {};
      acc = __builtin_amdgcn_mfma_f32_16x16x32_f16(af0, bf0, acc, 0, 0, 0);
      acc = __builtin_amdgcn_mfma_f32_16x16x32_f16(af1, bf1, acc, 0, 0, 0);
      const int jc = t * KT + jbase;
      ushort4_t s4;
#pragma unroll
      for (int r = 0; r < 4; ++r) {
        float sc = acc[r];
        s4[r] = h2us((_Float16)sc);
        if (jc <= i0 + lq * 4 + r) {
          mx[r] = fmaxf(mx[r], sc);
          unsigned hb = okey16(s4[r]) >> 8;
          atomicAdd(&hist[lq * 4 + r][hb >> 1], 1u << ((hb & 1) * 16));
        }
      }
      scr[t] = s4;
    }
  }

  // ---- row max: reduce over 16-lane group, then over 8 waves ----
#pragma unroll
  for (int g = 1; g <= 8; g <<= 1)
#pragma unroll
    for (int r = 0; r < 4; ++r) mx[r] = fmaxf(mx[r], __shfl_xor(mx[r], g));
  if (l16 == 0)
#pragma unroll
    for (int r = 0; r < 4; ++r) mredw[wv][lq * 4 + r] = mx[r];
  __syncthreads();
  if (tid < TQ) {
    float m = mredw[0][tid];
#pragma unroll
    for (int w = 1; w < 8; ++w) m = fmaxf(m, mredw[w][tid]);
    rowm[tid] = m;
  }

  // ---- parallel hi-byte select: 32 threads/row, 8 bins/thread, suffix scan -
  const int srow = tid >> 5, ts = tid & 31;
  {
    const int L = i0 + srow + 1;
    if (L > TOPK) {
      const unsigned* hrow = hist[srow];
      const int base_u = 124 - 4 * ts;  // bins 255-8ts .. 248-8ts descending
      unsigned h0 = hrow[base_u + 0], h1 = hrow[base_u + 1];
      unsigned h2 = hrow[base_u + 2], h3 = hrow[base_u + 3];
      int c[8] = {(int)(h3 >> 16), (int)(h3 & 0xffffu),
                  (int)(h2 >> 16), (int)(h2 & 0xffffu),
                  (int)(h1 >> 16), (int)(h1 & 0xffffu),
                  (int)(h0 >> 16), (int)(h0 & 0xffffu)};
      int ssum = 0;
#pragma unroll
      for (int k2 = 0; k2 < 8; ++k2) ssum += c[k2];
      int inc = ssum;
#pragma unroll
      for (int d = 1; d < 32; d <<= 1) {
        int o = __shfl_up(inc, d, 32);
        if (ts >= d) inc += o;
      }
      const int excl = inc - ssum;
      if (excl < TOPK && TOPK <= inc) {  // crossing lives in my 8 bins
        int cum = excl, k2 = 0;
#pragma unroll
        for (; k2 < 8; ++k2) {
          if (cum + c[k2] >= TOPK) break;
          cum += c[k2];
        }
        sh_b[srow] = 255 - 8 * ts - k2;
        sh_k[srow] = TOPK - cum;
      }
    } else if (ts == 0) {
      sh_b[srow] = 256;  // no hi-byte matches -> pass B no-op for this row
      sh_k[srow] = 0;
      tkA[srow] = 0;     // all valid entries survive
    }
  }
  __syncthreads();
#pragma unroll
  for (int u = 0; u < 4; ++u) ((unsigned*)hist)[u * 512 + tid] = 0;
  int bh4[4];
#pragma unroll
  for (int r = 0; r < 4; ++r) bh4[r] = sh_b[lq * 4 + r];
  __syncthreads();

  // ---- pass B: register scan -> lo-byte hist of the threshold bucket ----
#pragma unroll
  for (int t = 0; t < NTMAX; ++t) {
    if (t < ntile) {
      const int jc = t * KT + jbase;
      ushort4_t s4 = scr[t];
#pragma unroll
      for (int r = 0; r < 4; ++r) {
        if (jc <= i0 + lq * 4 + r) {
          unsigned key = okey16(s4[r]);
          if ((int)(key >> 8) == bh4[r]) {
            unsigned lb = key & 255u;
            atomicAdd(&hist[lq * 4 + r][lb >> 1], 1u << ((lb & 1) * 16));
          }
        }
      }
    }
  }
  __syncthreads();

  // ---- parallel lo-byte select -> exact fp16 threshold key ----
  {
    const int L = i0 + srow + 1;
    if (L > TOPK) {
      const int krem = sh_k[srow];
      const unsigned* hrow = hist[srow];
      const int base_u = 124 - 4 * ts;
      unsigned h0 = hrow[base_u + 0], h1 = hrow[base_u + 1];
      unsigned h2 = hrow[base_u + 2], h3 = hrow[base_u + 3];
      int c[8] = {(int)(h3 >> 16), (int)(h3 & 0xffffu),
                  (int)(h2 >> 16), (int)(h2 & 0xffffu),
                  (int)(h1 >> 16), (int)(h1 & 0xffffu),
                  (int)(h0 >> 16), (int)(h0 & 0xffffu)};
      int ssum = 0;
#pragma unroll
      for (int k2 = 0; k2 < 8; ++k2) ssum += c[k2];
      int inc = ssum;
#pragma unroll
      for (int d = 1; d < 32; d <<= 1) {
        int o = __shfl_up(inc, d, 32);
        if (ts >= d) inc += o;
      }
      const int excl = inc - ssum;
      if (excl < krem && krem <= inc) {
        int cum = excl, k2 = 0;
#pragma unroll
        for (; k2 < 8; ++k2) {
          if (cum + c[k2] >= krem) break;
          cum += c[k2];
        }
        tkA[srow] = ((unsigned)sh_b[srow] << 8) | (unsigned)(255 - 8 * ts - k2);
      }
    }
  }
  __syncthreads();

  // ---- pass C: register scan -> survivors + exp, direct append ----
  unsigned tk4[4]; float m4[4];
#pragma unroll
  for (int r = 0; r < 4; ++r) {
    tk4[r] = tkA[lq * 4 + r];
    m4[r]  = rowm[lq * 4 + r];
  }
  float lsum[4] = {0.f, 0.f, 0.f, 0.f};
#pragma unroll
  for (int t = 0; t < NTMAX; ++t) {
    if (t < ntile) {
      const int jc = t * KT + jbase;
      ushort4_t s4 = scr[t];
#pragma unroll
      for (int r = 0; r < 4; ++r) {
        if (jc <= i0 + lq * 4 + r) {
          unsigned short us = s4[r];
          if (okey16(us) >= tk4[r]) {
            float p = __expf((float)us2h(us) - m4[r]);
            lsum[r] += p;
            unsigned pos = atomicAdd(&cnt2[lq * 4 + r], 1u);
            if (pos < FCAP)
              final_[lq * 4 + r][pos] =
                  ((unsigned)h2us((_Float16)p) << 16) | (unsigned)jc;
          }
        }
      }
    }
  }
#pragma unroll
  for (int g = 1; g <= 8; g <<= 1)
#pragma unroll
    for (int r = 0; r < 4; ++r) lsum[r] += __shfl_xor(lsum[r], g);
  if (l16 == 0)
#pragma unroll
    for (int r = 0; r < 4; ++r) atomicAdd(&rowsum[lq * 4 + r], lsum[r]);
  __syncthreads();

  // ---- sparse p @ V: pad pair to max, then dense half-wave-split loop ----
  {
    const int r0 = wv * 2, r1 = wv * 2 + 1;
    const int n0 = (int)min(cnt2[r0], (unsigned)FCAP);
    const int n1 = (int)min(cnt2[r1], (unsigned)FCAP);
    const int nmx = n0 > n1 ? n0 : n1;
    const int nmin = n0 > n1 ? n1 : n0;
    const int shorter = n0 > n1 ? r1 : r0;
    // zero-pad shorter list (p=0 entries are inert); this wave is the only
    // consumer of rows r0,r1 -> intra-wave lgkmcnt ordering suffices
    for (int s = nmin + lane; s < nmx; s += 64) final_[shorter][s] = 0;

    const int r = r0 + (lane >> 5);     // lanes 0-31 -> r0, 32-63 -> r1
    const int d0 = (lane & 31) * 2;     // 2 dims per lane
    const float inv = 1.0f / rowsum[r];
    float a0 = 0.f, a1 = 0.f;
#pragma unroll 4
    for (int s = 0; s < nmx; ++s) {
      unsigned e = final_[r][s];
      const int jj = (int)(e & 0xffffu);
      const float p = (float)us2h((unsigned short)(e >> 16));
      const half2_t v2 = *(const half2_t*)(vbase + (size_t)jj * DH + d0);
      a0 += p * (float)v2[0];
      a1 += p * (float)v2[1];
    }
    const int b = bh >> 4, h = bh & 15;
    const int i = i0 + r;
    half2_t o2;
    o2[0] = (_Float16)(a0 * inv);
    o2[1] = (_Float16)(a1 * inv);
    *(half2_t*)(oh + ((size_t)(b * N_SEQ + i)) * DM + h * DH + d0) = o2;
  }
}

// ---------- launch ----------
extern "C" void kernel_launch(void* const* d_in, const int* in_sizes, int n_in,
                              void* d_out, int out_size, void* d_ws, size_t ws_size,
                              hipStream_t stream) {
  const float* x  = (const float*)d_in[0];
  const float* Wq = (const float*)d_in[1];
  const float* Wk = (const float*)d_in[2];
  const float* Wv = (const float*)d_in[3];
  const float* Wo = (const float*)d_in[4];
  float* out = (float*)d_out;
  char* ws = (char*)d_ws;

  const size_t MAT = (size_t)B_SZ * N_SEQ * DM;  // 4,194,304 elements
  const size_t WSZ = (size_t)DM * DM;            // 1,048,576

  float*    qh   = (float*)ws;                       ws += MAT * 4;   // 16 MB
  _Float16* xh   = (_Float16*)ws;                    ws += MAT * 2;   // 8 MB
  _Float16* kth  = (_Float16*)ws;                    ws += MAT * 2;
  _Float16* vth  = (_Float16*)ws;                    ws += MAT * 2;
  _Float16* Wt0  = (_Float16*)ws;                    ws += WSZ * 2;
  _Float16* Wt1  = (_Float16*)ws;                    ws += WSZ * 2;
  _Float16* Wt2  = (_Float16*)ws;                    ws += WSZ * 2;
  _Float16* Wt3  = (_Float16*)ws;                    ws += WSZ * 2;
  float*    wre  = (float*)ws;                       ws += KC * 4;
  float*    wim  = (float*)ws;                       ws += KC * 4;
  float*    cosT = (float*)ws;                       ws += (size_t)N_SEQ * KC * 4;
  float*    sinT = (float*)ws;                       ws += (size_t)N_SEQ * KC * 4;
  _Float16* oh   = xh;  // xh dead after QKV GEMM; reuse for attn output

  setup_kernel<<<4096 + 256 + 1, 256, 0, stream>>>(x, xh, cosT, sinT, wre, wim);
  transpose_cast<<<dim3(16, 16, 4), 256, 0, stream>>>(Wq, Wk, Wv, Wo,
                                                      Wt0, Wt1, Wt2, Wt3);
  gemm_qkv_fused<<<dim3(256, 1, 3), 256, 0, stream>>>(
      xh, Wt0, Wt1, Wt2, wre, wim, cosT, sinT, qh, kth, vth);
  attn_kernel<<<dim3(N_SEQ / TQ, B_SZ * H_HEADS), 512, 0, stream>>>(
      qh, kth, vth, oh);
  gemm_out_mfma<<<dim3(256), 256, 0, stream>>>(oh, Wt3, out);
}

// Round 13
// 353.271 us; speedup vs baseline: 1.5958x; 1.0094x over previous
//
#include <hip/hip_runtime.h>
#include <math.h>

#define B_SZ 2
#define N_SEQ 2048
#define DM 1024
#define H_HEADS 16
#define DH 64
#define KC 32
#define TOPK 100
#define TQ 16
#define KT 128
#define NTMAX 16
#define FCAP 192
#define CSTRIDE 132

typedef _Float16 half2_t __attribute__((ext_vector_type(2)));
typedef _Float16 half4_t __attribute__((ext_vector_type(4)));
typedef _Float16 half8_t __attribute__((ext_vector_type(8)));
typedef float floatx4 __attribute__((ext_vector_type(4)));
typedef unsigned short ushort4_t __attribute__((ext_vector_type(4)));

// ---------- helpers ----------
__device__ __forceinline__ unsigned short h2us(_Float16 h) {
  unsigned short u; __builtin_memcpy(&u, &h, 2); return u;
}
__device__ __forceinline__ _Float16 us2h(unsigned short u) {
  _Float16 h; __builtin_memcpy(&h, &u, 2); return h;
}
__device__ __forceinline__ unsigned okey16(unsigned short us) {
  return (us & 0x8000u) ? (unsigned)(unsigned short)~us
                        : (unsigned)(us | 0x8000u);
}

// async global->LDS, 16 B per lane; lds_base must be wave-uniform
__device__ __forceinline__ void stage16(const _Float16* g, _Float16* lds_base,
                                        int lane) {
#if __has_builtin(__builtin_amdgcn_global_load_lds)
  __builtin_amdgcn_global_load_lds(
      (const __attribute__((address_space(1))) void*)g,
      (__attribute__((address_space(3))) void*)lds_base, 16, 0, 0);
#else
  *(half8_t*)(lds_base + lane * 8) = *(const half8_t*)g;
#endif
}

// ---------- merged setup: cast_x (4096) + rope (256) + const (1) +
// transpose-cast of the four weight matrices (1024 blocks) ----------
__global__ __launch_bounds__(256) void setup_kernel(
    const float* __restrict__ x, _Float16* __restrict__ xh,
    float* __restrict__ cosT, float* __restrict__ sinT,
    float* __restrict__ wre, float* __restrict__ wim,
    const float* __restrict__ W0, const float* __restrict__ W1,
    const float* __restrict__ W2, const float* __restrict__ W3,
    _Float16* __restrict__ T0, _Float16* __restrict__ T1,
    _Float16* __restrict__ T2, _Float16* __restrict__ T3) {
  __shared__ float t[64][65];   // transpose tile (also covers g0s use)
  __shared__ double g0s;
  const int bi = blockIdx.x;
  const int tid = threadIdx.x;
  if (bi < 4096) {
    // cast x fp32 -> fp16
    int idx = bi * 256 + tid;
    float4 v = ((const float4*)x)[idx];
    half4_t h;
    h[0] = (_Float16)v.x; h[1] = (_Float16)v.y;
    h[2] = (_Float16)v.z; h[3] = (_Float16)v.w;
    ((half4_t*)xh)[idx] = h;
  } else if (bi < 4096 + 256) {
    // RoPE tables (f32 math; err far under fp16 quantization downstream)
    int idx = (bi - 4096) * 256 + tid;  // 65536 = 2048*32
    int kk = idx & 31, n = idx >> 5;
    float f = -(float)kk * (13.2877123795494f / 32.0f);
    float inv_freq = exp2f(f);
    float ph = (float)n * inv_freq;
    cosT[idx] = cosf(ph);
    sinT[idx] = sinf(ph);
  } else if (bi == 4096 + 256) {
    // Riemann-zero weights (32 active threads)
    const int k = tid;
    const double PI = 3.14159265358979323846;
    const double E_ = 2.71828182845904523536;
    double tt = 0.0;
    if (k < 32) {
      double n = (double)(k + 1);
      tt = 10.0 + 6.0 * n;
      for (int it = 0; it < 16; ++it) {
        double f  = tt / (2.0 * PI) * log(tt / (2.0 * PI * E_)) - (n - 0.875);
        double fp = log(tt / (2.0 * PI)) / (2.0 * PI);
        tt = tt - f / fp;
      }
      if (k == 0) g0s = tt;
    }
    __syncthreads();
    if (k < 32) {
      double g = tt / g0s;
      double denom = 0.25 + g * g;
      wre[k] = (float)(0.5 / denom);
      wim[k] = (float)(-g / denom);
    }
  } else {
    // transpose-cast W (fp32 [k][n]) -> Wt (fp16 [n][k])
    const int tb = bi - (4096 + 256 + 1);   // 0..1023
    const int bx = tb & 15, by = (tb >> 4) & 15, z = tb >> 8;
    const float* W; _Float16* T;
    switch (z) {
      case 0: W = W0; T = T0; break;
      case 1: W = W1; T = T1; break;
      case 2: W = W2; T = T2; break;
      default: W = W3; T = T3; break;
    }
    const int c = tid & 15, rr = tid >> 4;
#pragma unroll
    for (int i = 0; i < 4; ++i) {
      int k = rr + i * 16;
      float4 v = *(const float4*)(W + (size_t)(bx * 64 + k) * DM + by * 64 + c * 4);
      t[k][c * 4 + 0] = v.x; t[k][c * 4 + 1] = v.y;
      t[k][c * 4 + 2] = v.z; t[k][c * 4 + 3] = v.w;
    }
    __syncthreads();
#pragma unroll
    for (int i = 0; i < 4; ++i) {
      int n = rr + i * 16;
      half4_t h;
      h[0] = (_Float16)t[c * 4 + 0][n];
      h[1] = (_Float16)t[c * 4 + 1][n];
      h[2] = (_Float16)t[c * 4 + 2][n];
      h[3] = (_Float16)t[c * 4 + 3][n];
      *(half4_t*)(T + (size_t)(by * 64 + n) * DM + bx * 64 + c * 4) = h;
    }
  }
}

// ---------- shared GEMM main loop (BK=64, rule-21 XOR swizzle, R4-verified) -
__device__ __forceinline__ void gemm_loop(const _Float16* __restrict__ A,
                                          const _Float16* __restrict__ Bt,
                                          _Float16* As, _Float16* Bs,
                                          int bm, int bn,
                                          floatx4 (&acc)[4][4]) {
  const int tid = threadIdx.x;
  const int wave = tid >> 6, lane = tid & 63;
  const int wm = wave >> 1, wn = wave & 1;
  const int grow = lane >> 3;           // row within 8-row staging segment
  const int gch  = (lane & 7) ^ grow;   // pre-swizzled source chunk (8 halves)
  const int l16 = lane & 15, lq = lane >> 4;
  const int sw  = l16 & 7;              // row&7 for swizzled reads

  for (int k0 = 0; k0 < DM; k0 += 64) {
    __syncthreads();
#pragma unroll
    for (int s = 0; s < 4; ++s) {
      const int seg = wave * 4 + s;  // 8-row segment of the 128-row tile
      stage16(A + (size_t)(bm + seg * 8 + grow) * DM + k0 + gch * 8,
              As + seg * 512, lane);
      stage16(Bt + (size_t)(bn + seg * 8 + grow) * DM + k0 + gch * 8,
              Bs + seg * 512, lane);
    }
    __syncthreads();
    half8_t af[2][4], bf[2][4];
#pragma unroll
    for (int kk2 = 0; kk2 < 2; ++kk2) {
#pragma unroll
      for (int mi = 0; mi < 4; ++mi)
        af[kk2][mi] = *(const half8_t*)(As + (wm * 64 + mi * 16 + l16) * 64 +
                                        ((kk2 * 4 + lq) ^ sw) * 8);
#pragma unroll
      for (int ni = 0; ni < 4; ++ni)
        bf[kk2][ni] = *(const half8_t*)(Bs + (wn * 64 + ni * 16 + l16) * 64 +
                                        ((kk2 * 4 + lq) ^ sw) * 8);
    }
#pragma unroll
    for (int kk2 = 0; kk2 < 2; ++kk2)
#pragma unroll
      for (int mi = 0; mi < 4; ++mi)
#pragma unroll
        for (int ni = 0; ni < 4; ++ni)
          acc[mi][ni] = __builtin_amdgcn_mfma_f32_16x16x32_f16(
              af[kk2][mi], bf[kk2][ni], acc[mi][ni], 0, 0, 0);
  }
}

// XCD-aware bijective swizzle for a 256-block z-plane (m204; 256 = 8*32)
__device__ __forceinline__ void xcd_decode(int flat, int& bm, int& bn) {
  const int o = (flat & 7) * 32 + (flat >> 3);
  bm = (o >> 3) * 128;
  bn = (o & 7) * 128;
}

// ---------- fused QKV GEMM: LDS-coalesced epilogue (RoPE + w + layout) ------
__global__ __launch_bounds__(256) void gemm_qkv_fused(
    const _Float16* __restrict__ xh, const _Float16* __restrict__ Wt0,
    const _Float16* __restrict__ Wt1, const _Float16* __restrict__ Wt2,
    const float* __restrict__ wre, const float* __restrict__ wim,
    const float* __restrict__ cosT, const float* __restrict__ sinT,
    float* __restrict__ qhO, _Float16* __restrict__ kthO,
    _Float16* __restrict__ vthO) {
  __shared__ __align__(16) _Float16 smem[2 * 128 * 64];  // 32 KB
  _Float16* As = smem;
  _Float16* Bs = smem + 128 * 64;
  const int z = blockIdx.z;
  const _Float16* Bt = (z == 0) ? Wt0 : (z == 1) ? Wt1 : Wt2;
  int bm, bn;
  xcd_decode(blockIdx.x, bm, bn);
  floatx4 acc[4][4] = {};
  gemm_loop(xh, Bt, As, Bs, bm, bn, acc);
  __syncthreads();  // all ds_reads of the last tile done before smem reuse

  float* cbuf = (float*)smem;  // [32][CSTRIDE] = 16896 B, fits in 32 KB
  const int tid = threadIdx.x;
  const int wave = tid >> 6, lane = tid & 63;
  const int wm = wave >> 1, wn = wave & 1;
  const int l16 = lane & 15, lq = lane >> 4;

  // read-phase mapping: 2 heads x 32 rows x 4 kk-octets
  const int h2 = tid >> 7, t7 = tid & 127;
  const int rl = t7 >> 2, q4 = t7 & 3;
  const int hh = (bn >> 6) + h2;
  const int row_nom = bm + (rl >> 4) * 64 + (rl & 15);  // + mi*16 in loop
  const int kk0 = q4 * 8;

#pragma unroll
  for (int mi = 0; mi < 4; ++mi) {
    // scatter: 32 rows x 128 cols of C, f32
#pragma unroll
    for (int ni = 0; ni < 4; ++ni)
#pragma unroll
      for (int r = 0; r < 4; ++r)
        cbuf[(wm * 16 + lq * 4 + r) * CSTRIDE + wn * 64 + ni * 16 + l16] =
            acc[mi][ni][r];
    __syncthreads();

    const int row = row_nom + mi * 16;
    const int b = row >> 11, n = row & (N_SEQ - 1);
    const float* crow = cbuf + rl * CSTRIDE + h2 * 64;
    const size_t base = ((size_t)((b * H_HEADS + hh) * N_SEQ + n)) * DH;

    if (z == 2) {
      const int d0 = q4 * 16;
      half8_t o0, o1;
#pragma unroll
      for (int j = 0; j < 8; ++j) {
        o0[j] = (_Float16)crow[d0 + j];
        o1[j] = (_Float16)crow[d0 + 8 + j];
      }
      *(half8_t*)(vthO + base + d0) = o0;
      *(half8_t*)(vthO + base + d0 + 8) = o1;
    } else if (z == 1) {
      const float sj = 0.125f * sqrtf(1.0f + (float)n);
      half8_t ore, oim;
#pragma unroll
      for (int j = 0; j < 8; ++j) {
        const int kk = kk0 + j;
        const float re = crow[2 * kk], im = crow[2 * kk + 1];
        const float cp = cosT[n * 32 + kk], sp = sinT[n * 32 + kk];
        ore[j] = (_Float16)((cp * re + sp * im) * sj);
        oim[j] = (_Float16)((cp * im - sp * re) * sj);
      }
      *(half8_t*)(kthO + base + kk0) = ore;
      *(half8_t*)(kthO + base + 32 + kk0) = oim;
    } else {
      float ore[8], oim[8];
#pragma unroll
      for (int j = 0; j < 8; ++j) {
        const int kk = kk0 + j;
        const float re = crow[2 * kk], im = crow[2 * kk + 1];
        const float cp = cosT[n * 32 + kk], sp = sinT[n * 32 + kk];
        const float t_re = cp * re + sp * im;
        const float t_im = cp * im - sp * re;
        const float wr = wre[kk], wi = wim[kk];
        ore[j] = wr * t_re - wi * t_im;
        oim[j] = wr * t_im + wi * t_re;
      }
      float4 v0 = {ore[0], ore[1], ore[2], ore[3]};
      float4 v1 = {ore[4], ore[5], ore[6], ore[7]};
      float4 v2 = {oim[0], oim[1], oim[2], oim[3]};
      float4 v3 = {oim[4], oim[5], oim[6], oim[7]};
      *(float4*)(qhO + base + kk0) = v0;
      *(float4*)(qhO + base + kk0 + 4) = v1;
      *(float4*)(qhO + base + 32 + kk0) = v2;
      *(float4*)(qhO + base + 32 + kk0 + 4) = v3;
    }
    if (mi < 3) __syncthreads();
  }
}

// ---------- output GEMM (plain epilogue) ----------
__global__ __launch_bounds__(256) void gemm_out_mfma(
    const _Float16* __restrict__ A, const _Float16* __restrict__ Bt,
    float* __restrict__ C) {
  __shared__ _Float16 As[128 * 64];
  __shared__ _Float16 Bs[128 * 64];
  int bm, bn;
  xcd_decode(blockIdx.x, bm, bn);
  floatx4 acc[4][4] = {};
  gemm_loop(A, Bt, As, Bs, bm, bn, acc);
  const int tid = threadIdx.x;
  const int wave = tid >> 6, lane = tid & 63;
  const int wm = wave >> 1, wn = wave & 1;
  const int l16 = lane & 15, lq = lane >> 4;
#pragma unroll
  for (int mi = 0; mi < 4; ++mi)
#pragma unroll
    for (int ni = 0; ni < 4; ++ni) {
      const int col = bn + wn * 64 + ni * 16 + l16;
#pragma unroll
      for (int r = 0; r < 4; ++r) {
        const int row = bm + wm * 64 + mi * 16 + lq * 4 + r;
        C[(size_t)row * DM + col] = acc[mi][ni][r];
      }
    }
}

// ---------- attention: R12 structure + full/boundary tile split -------------
// Causal guard only evaluated in the ONE boundary tile per block
// (nfull=(i0+1)>>7 full tiles need no mask; exactly one partial follows).
// Both branch arms are block-uniform with compile-time t -> scr[] stays
// statically indexed (rule #20). PV: padded half-wave split (R12, verified).
__global__ __launch_bounds__(512, 4) void attn_kernel(
    const float* __restrict__ qh, const _Float16* __restrict__ kth,
    const _Float16* __restrict__ vth, _Float16* __restrict__ oh) {
  __shared__ unsigned hist[TQ][128];                  // 8192 B packed 16-bit
  __shared__ unsigned final_[TQ][FCAP];               // 12288 B (p<<16)|j
  __shared__ float mredw[8][TQ];                      // 512 B
  __shared__ float rowm[TQ], rowsum[TQ];
  __shared__ unsigned cnt2[TQ], tkA[TQ];
  __shared__ int sh_b[TQ], sh_k[TQ];

  const int tile = gridDim.x - 1 - blockIdx.x;  // heavy blocks first
  const int bh   = blockIdx.y;                  // 0..31
  const int i0   = tile * TQ;
  const int tid  = threadIdx.x;
  const int wv = tid >> 6, lane = tid & 63;
  const int l16 = lane & 15, lq = lane >> 4;
  const int jbase = wv * 16 + l16;              // col within a 128-wide tile

  const _Float16* kbase = kth + (size_t)bh * N_SEQ * DH;
  const _Float16* vbase = vth + (size_t)bh * N_SEQ * DH;
  // per-lane K fragment base: row jbase, halves [lq*8..lq*8+8) and +32
  const _Float16* kfrag = kbase + (size_t)jbase * DH + lq * 8;

  // ---- init ----
#pragma unroll
  for (int u = 0; u < 4; ++u) ((unsigned*)hist)[u * 512 + tid] = 0;
  if (tid < TQ) { cnt2[tid] = 0; rowsum[tid] = 0.f; }

  // ---- A-fragment: row m=l16 -> q row i0+l16, k=lq*8+j (K=64 via 2 mfma) ----
  half8_t af0, af1;
  {
    const float* qrow = qh + ((size_t)(bh * N_SEQ + i0 + l16)) * DH;
    const float rs = rsqrtf(1.0f + (float)(i0 + l16));
    float4 a0 = *(const float4*)(qrow + lq * 8);
    float4 a1 = *(const float4*)(qrow + lq * 8 + 4);
    float4 b0 = *(const float4*)(qrow + 32 + lq * 8);
    float4 b1 = *(const float4*)(qrow + 32 + lq * 8 + 4);
    af0[0] = (_Float16)(a0.x * rs); af0[1] = (_Float16)(a0.y * rs);
    af0[2] = (_Float16)(a0.z * rs); af0[3] = (_Float16)(a0.w * rs);
    af0[4] = (_Float16)(a1.x * rs); af0[5] = (_Float16)(a1.y * rs);
    af0[6] = (_Float16)(a1.z * rs); af0[7] = (_Float16)(a1.w * rs);
    af1[0] = (_Float16)(b0.x * rs); af1[1] = (_Float16)(b0.y * rs);
    af1[2] = (_Float16)(b0.z * rs); af1[3] = (_Float16)(b0.w * rs);
    af1[4] = (_Float16)(b1.x * rs); af1[5] = (_Float16)(b1.y * rs);
    af1[6] = (_Float16)(b1.z * rs); af1[7] = (_Float16)(b1.w * rs);
  }

  const int ntile = (i0 + TQ + KT - 1) / KT;  // <= 16; exactly ntile-nfull==1
  const int nfull = (i0 + 1) >> 7;            // tiles needing no causal mask

  ushort4_t scr[NTMAX];  // 64 fp16 scores, static indexing only
  float mx[4] = {-INFINITY, -INFINITY, -INFINITY, -INFINITY};

  __syncthreads();  // hist zero-init visible to all before pass A atomics

  // ---- pass A: barrier-free MFMA sweep. scores -> regs, hist, row max ----
#pragma unroll
  for (int t = 0; t < NTMAX; ++t) {
    if (t < nfull) {  // full tile: no causal guard (always valid)
      const _Float16* kp = kfrag + (size_t)t * KT * DH;
      half8_t bf0 = *(const half8_t*)kp;
      half8_t bf1 = *(const half8_t*)(kp + 32);
      floatx4 acc = {};
      acc = __builtin_amdgcn_mfma_f32_16x16x32_f16(af0, bf0, acc, 0, 0, 0);
      acc = __builtin_amdgcn_mfma_f32_16x16x32_f16(af1, bf1, acc, 0, 0, 0);
      ushort4_t s4;
#pragma unroll
      for (int r = 0; r < 4; ++r) {
        float sc = acc[r];
        s4[r] = h2us((_Float16)sc);
        mx[r] = fmaxf(mx[r], sc);
        unsigned hb = okey16(s4[r]) >> 8;
        atomicAdd(&hist[lq * 4 + r][hb >> 1], 1u << ((hb & 1) * 16));
      }
      scr[t] = s4;
    } else if (t < ntile) {  // the single boundary tile: guarded
      const _Float16* kp = kfrag + (size_t)t * KT * DH;
      half8_t bf0 = *(const half8_t*)kp;
      half8_t bf1 = *(const half8_t*)(kp + 32);
      floatx4 acc = {};
      acc = __builtin_amdgcn_mfma_f32_16x16x32_f16(af0, bf0, acc, 0, 0, 0);
      acc = __builtin_amdgcn_mfma_f32_16x16x32_f16(af1, bf1, acc, 0, 0, 0);
      const int jc = t * KT + jbase;
      ushort4_t s4;
#pragma unroll
      for (int r = 0; r < 4; ++r) {
        float sc = acc[r];
        s4[r] = h2us((_Float16)sc);
        if (jc <= i0 + lq * 4 + r) {
          mx[r] = fmaxf(mx[r], sc);
          unsigned hb = okey16(s4[r]) >> 8;
          atomicAdd(&hist[lq * 4 + r][hb >> 1], 1u << ((hb & 1) * 16));
        }
      }
      scr[t] = s4;
    }
  }

  // ---- row max: reduce over 16-lane group, then over 8 waves ----
#pragma unroll
  for (int g = 1; g <= 8; g <<= 1)
#pragma unroll
    for (int r = 0; r < 4; ++r) mx[r] = fmaxf(mx[r], __shfl_xor(mx[r], g));
  if (l16 == 0)
#pragma unroll
    for (int r = 0; r < 4; ++r) mredw[wv][lq * 4 + r] = mx[r];
  __syncthreads();
  if (tid < TQ) {
    float m = mredw[0][tid];
#pragma unroll
    for (int w = 1; w < 8; ++w) m = fmaxf(m, mredw[w][tid]);
    rowm[tid] = m;
  }

  // ---- parallel hi-byte select: 32 threads/row, 8 bins/thread, suffix scan -
  const int srow = tid >> 5, ts = tid & 31;
  {
    const int L = i0 + srow + 1;
    if (L > TOPK) {
      const unsigned* hrow = hist[srow];
      const int base_u = 124 - 4 * ts;  // bins 255-8ts .. 248-8ts descending
      unsigned h0 = hrow[base_u + 0], h1 = hrow[base_u + 1];
      unsigned h2 = hrow[base_u + 2], h3 = hrow[base_u + 3];
      int c[8] = {(int)(h3 >> 16), (int)(h3 & 0xffffu),
                  (int)(h2 >> 16), (int)(h2 & 0xffffu),
                  (int)(h1 >> 16), (int)(h1 & 0xffffu),
                  (int)(h0 >> 16), (int)(h0 & 0xffffu)};
      int ssum = 0;
#pragma unroll
      for (int k2 = 0; k2 < 8; ++k2) ssum += c[k2];
      int inc = ssum;
#pragma unroll
      for (int d = 1; d < 32; d <<= 1) {
        int o = __shfl_up(inc, d, 32);
        if (ts >= d) inc += o;
      }
      const int excl = inc - ssum;
      if (excl < TOPK && TOPK <= inc) {  // crossing lives in my 8 bins
        int cum = excl, k2 = 0;
#pragma unroll
        for (; k2 < 8; ++k2) {
          if (cum + c[k2] >= TOPK) break;
          cum += c[k2];
        }
        sh_b[srow] = 255 - 8 * ts - k2;
        sh_k[srow] = TOPK - cum;
      }
    } else if (ts == 0) {
      sh_b[srow] = 256;  // no hi-byte matches -> pass B no-op for this row
      sh_k[srow] = 0;
      tkA[srow] = 0;     // all valid entries survive
    }
  }
  __syncthreads();
#pragma unroll
  for (int u = 0; u < 4; ++u) ((unsigned*)hist)[u * 512 + tid] = 0;
  int bh4[4];
#pragma unroll
  for (int r = 0; r < 4; ++r) bh4[r] = sh_b[lq * 4 + r];
  __syncthreads();

  // ---- pass B: register scan -> lo-byte hist of the threshold bucket ----
#pragma unroll
  for (int t = 0; t < NTMAX; ++t) {
    if (t < nfull) {  // full tile: no causal guard
      ushort4_t s4 = scr[t];
#pragma unroll
      for (int r = 0; r < 4; ++r) {
        unsigned key = okey16(s4[r]);
        if ((int)(key >> 8) == bh4[r]) {
          unsigned lb = key & 255u;
          atomicAdd(&hist[lq * 4 + r][lb >> 1], 1u << ((lb & 1) * 16));
        }
      }
    } else if (t < ntile) {
      const int jc = t * KT + jbase;
      ushort4_t s4 = scr[t];
#pragma unroll
      for (int r = 0; r < 4; ++r) {
        if (jc <= i0 + lq * 4 + r) {
          unsigned key = okey16(s4[r]);
          if ((int)(key >> 8) == bh4[r]) {
            unsigned lb = key & 255u;
            atomicAdd(&hist[lq * 4 + r][lb >> 1], 1u << ((lb & 1) * 16));
          }
        }
      }
    }
  }
  __syncthreads();

  // ---- parallel lo-byte select -> exact fp16 threshold key ----
  {
    const int L = i0 + srow + 1;
    if (L > TOPK) {
      const int krem = sh_k[srow];
      const unsigned* hrow = hist[srow];
      const int base_u = 124 - 4 * ts;
      unsigned h0 = hrow[base_u + 0], h1 = hrow[base_u + 1];
      unsigned h2 = hrow[base_u + 2], h3 = hrow[base_u + 3];
      int c[8] = {(int)(h3 >> 16), (int)(h3 & 0xffffu),
                  (int)(h2 >> 16), (int)(h2 & 0xffffu),
                  (int)(h1 >> 16), (int)(h1 & 0xffffu),
                  (int)(h0 >> 16), (int)(h0 & 0xffffu)};
      int ssum = 0;
#pragma unroll
      for (int k2 = 0; k2 < 8; ++k2) ssum += c[k2];
      int inc = ssum;
#pragma unroll
      for (int d = 1; d < 32; d <<= 1) {
        int o = __shfl_up(inc, d, 32);
        if (ts >= d) inc += o;
      }
      const int excl = inc - ssum;
      if (excl < krem && krem <= inc) {
        int cum = excl, k2 = 0;
#pragma unroll
        for (; k2 < 8; ++k2) {
          if (cum + c[k2] >= krem) break;
          cum += c[k2];
        }
        tkA[srow] = ((unsigned)sh_b[srow] << 8) | (unsigned)(255 - 8 * ts - k2);
      }
    }
  }
  __syncthreads();

  // ---- pass C: register scan -> survivors + exp, direct append ----
  unsigned tk4[4]; float m4[4];
#pragma unroll
  for (int r = 0; r < 4; ++r) {
    tk4[r] = tkA[lq * 4 + r];
    m4[r]  = rowm[lq * 4 + r];
  }
  float lsum[4] = {0.f, 0.f, 0.f, 0.f};
#pragma unroll
  for (int t = 0; t < NTMAX; ++t) {
    if (t < nfull) {  // full tile: no causal guard
      const int jc = t * KT + jbase;
      ushort4_t s4 = scr[t];
#pragma unroll
      for (int r = 0; r < 4; ++r) {
        unsigned short us = s4[r];
        if (okey16(us) >= tk4[r]) {
          float p = __expf((float)us2h(us) - m4[r]);
          lsum[r] += p;
          unsigned pos = atomicAdd(&cnt2[lq * 4 + r], 1u);
          if (pos < FCAP)
            final_[lq * 4 + r][pos] =
                ((unsigned)h2us((_Float16)p) << 16) | (unsigned)jc;
        }
      }
    } else if (t < ntile) {
      const int jc = t * KT + jbase;
      ushort4_t s4 = scr[t];
#pragma unroll
      for (int r = 0; r < 4; ++r) {
        if (jc <= i0 + lq * 4 + r) {
          unsigned short us = s4[r];
          if (okey16(us) >= tk4[r]) {
            float p = __expf((float)us2h(us) - m4[r]);
            lsum[r] += p;
            unsigned pos = atomicAdd(&cnt2[lq * 4 + r], 1u);
            if (pos < FCAP)
              final_[lq * 4 + r][pos] =
                  ((unsigned)h2us((_Float16)p) << 16) | (unsigned)jc;
          }
        }
      }
    }
  }
#pragma unroll
  for (int g = 1; g <= 8; g <<= 1)
#pragma unroll
    for (int r = 0; r < 4; ++r) lsum[r] += __shfl_xor(lsum[r], g);
  if (l16 == 0)
#pragma unroll
    for (int r = 0; r < 4; ++r) atomicAdd(&rowsum[lq * 4 + r], lsum[r]);
  __syncthreads();

  // ---- sparse p @ V: pad pair to max, then dense half-wave-split loop ----
  {
    const int r0 = wv * 2, r1 = wv * 2 + 1;
    const int n0 = (int)min(cnt2[r0], (unsigned)FCAP);
    const int n1 = (int)min(cnt2[r1], (unsigned)FCAP);
    const int nmx = n0 > n1 ? n0 : n1;
    const int nmin = n0 > n1 ? n1 : n0;
    const int shorter = n0 > n1 ? r1 : r0;
    // zero-pad shorter list (p=0 entries are inert); this wave is the only
    // consumer of rows r0,r1 -> intra-wave lgkmcnt ordering suffices
    for (int s = nmin + lane; s < nmx; s += 64) final_[shorter][s] = 0;

    const int r = r0 + (lane >> 5);     // lanes 0-31 -> r0, 32-63 -> r1
    const int d0 = (lane & 31) * 2;     // 2 dims per lane
    const float inv = 1.0f / rowsum[r];
    float a0 = 0.f, a1 = 0.f;
#pragma unroll 4
    for (int s = 0; s < nmx; ++s) {
      unsigned e = final_[r][s];
      const int jj = (int)(e & 0xffffu);
      const float p = (float)us2h((unsigned short)(e >> 16));
      const half2_t v2 = *(const half2_t*)(vbase + (size_t)jj * DH + d0);
      a0 += p * (float)v2[0];
      a1 += p * (float)v2[1];
    }
    const int b = bh >> 4, h = bh & 15;
    const int i = i0 + r;
    half2_t o2;
    o2[0] = (_Float16)(a0 * inv);
    o2[1] = (_Float16)(a1 * inv);
    *(half2_t*)(oh + ((size_t)(b * N_SEQ + i)) * DM + h * DH + d0) = o2;
  }
}

// ---------- launch ----------
extern "C" void kernel_launch(void* const* d_in, const int* in_sizes, int n_in,
                              void* d_out, int out_size, void* d_ws, size_t ws_size,
                              hipStream_t stream) {
  const float* x  = (const float*)d_in[0];
  const float* Wq = (const float*)d_in[1];
  const float* Wk = (const float*)d_in[2];
  const float* Wv = (const float*)d_in[3];
  const float* Wo = (const float*)d_in[4];
  float* out = (float*)d_out;
  char* ws = (char*)d_ws;

  const size_t MAT = (size_t)B_SZ * N_SEQ * DM;  // 4,194,304 elements
  const size_t WSZ = (size_t)DM * DM;            // 1,048,576

  float*    qh   = (float*)ws;                       ws += MAT * 4;   // 16 MB
  _Float16* xh   = (_Float16*)ws;                    ws += MAT * 2;   // 8 MB
  _Float16* kth  = (_Float16*)ws;                    ws += MAT * 2;
  _Float16* vth  = (_Float16*)ws;                    ws += MAT * 2;
  _Float16* Wt0  = (_Float16*)ws;                    ws += WSZ * 2;
  _Float16* Wt1  = (_Float16*)ws;                    ws += WSZ * 2;
  _Float16* Wt2  = (_Float16*)ws;                    ws += WSZ * 2;
  _Float16* Wt3  = (_Float16*)ws;                    ws += WSZ * 2;
  float*    wre  = (float*)ws;                       ws += KC * 4;
  float*    wim  = (float*)ws;                       ws += KC * 4;
  float*    cosT = (float*)ws;                       ws += (size_t)N_SEQ * KC * 4;
  float*    sinT = (float*)ws;                       ws += (size_t)N_SEQ * KC * 4;
  _Float16* oh   = xh;  // xh dead after QKV GEMM; reuse for attn output

  setup_kernel<<<4096 + 256 + 1 + 1024, 256, 0, stream>>>(
      x, xh, cosT, sinT, wre, wim, Wq, Wk, Wv, Wo, Wt0, Wt1, Wt2, Wt3);
  gemm_qkv_fused<<<dim3(256, 1, 3), 256, 0, stream>>>(
      xh, Wt0, Wt1, Wt2, wre, wim, cosT, sinT, qh, kth, vth);
  attn_kernel<<<dim3(N_SEQ / TQ, B_SZ * H_HEADS), 512, 0, stream>>>(
      qh, kth, vth, oh);
  gemm_out_mfma<<<dim3(256), 256, 0, stream>>>(oh, Wt3, out);
}